// Round 7
// baseline (272.101 us; speedup 1.0000x reference)
//
#include <hip/hip_runtime.h>
#include <hip/hip_bf16.h>

typedef __bf16 bf16_t;
typedef __bf16 bf16x4 __attribute__((ext_vector_type(4)));
typedef __bf16 bf16x8 __attribute__((ext_vector_type(8)));
typedef float f32x4 __attribute__((ext_vector_type(4)));

#define AS1(p) ((const __attribute__((address_space(1))) void*)(p))
#define AS3(p) ((__attribute__((address_space(3))) void*)(p))

__device__ __forceinline__ f32x4 mfma16(bf16x8 a, bf16x8 b, f32x4 c) {
  return __builtin_amdgcn_mfma_f32_16x16x32_bf16(a, b, c, 0, 0, 0);
}

// ---- fused prep: x cast + 4 weight transposes + combined bias build ----
// blocks 0..255: Wq->WqT ; 256..271: Wk->WkvT[0:64] ; 272..287: Wv->WkvT[64:128] ;
// 288..543: Wo->WoT ; 544: bq->bqkv[0:1024] ; 545: bk/bv->bqkv[1024:1152] ;
// 546+: x -> bf16.
__global__ void prep(const float* __restrict__ x, const float* __restrict__ Wq,
                     const float* __restrict__ Wk, const float* __restrict__ Wv,
                     const float* __restrict__ Wo, const float* __restrict__ bq,
                     const float* __restrict__ bk, const float* __restrict__ bv,
                     bf16_t* __restrict__ xb, bf16_t* __restrict__ WqT,
                     bf16_t* __restrict__ WkvT, bf16_t* __restrict__ WoT,
                     float* __restrict__ bqkv) {
  const int u = blockIdx.x;
  if (u >= 546) {  // x cast: 8192*1024 f32 -> bf16, 4/lane
    int i = ((u - 546) * 256 + threadIdx.x) * 4;
    float4 v = *(const float4*)(x + i);
    bf16x4 o = {(bf16_t)v.x, (bf16_t)v.y, (bf16_t)v.z, (bf16_t)v.w};
    *(bf16x4*)(xb + i) = o;
    return;
  }
  if (u == 544) {  // bq copy (1024 f32)
    int i = threadIdx.x * 4;
    *(float4*)(bqkv + i) = *(const float4*)(bq + i);
    return;
  }
  if (u == 545) {  // bk/bv pack
    if (threadIdx.x < 128)
      bqkv[1024 + threadIdx.x] =
          (threadIdx.x < 64) ? bk[threadIdx.x] : bv[threadIdx.x - 64];
    return;
  }
  const float* W; bf16_t* Wt; int N, bx, by;
  if (u < 256)      { W = Wq; Wt = WqT;              N = 1024; bx = u & 15;         by = u >> 4; }
  else if (u < 272) { W = Wk; Wt = WkvT;             N = 64;   bx = 0;              by = u - 256; }
  else if (u < 288) { W = Wv; Wt = WkvT + 64 * 1024; N = 64;   bx = 0;              by = u - 272; }
  else              { W = Wo; Wt = WoT;              N = 1024; bx = (u - 288) & 15; by = (u - 288) >> 4; }
  __shared__ float t[64][65];
  const int n0 = bx * 64, k0 = by * 64;
  const int tx = threadIdx.x & 63, ty = threadIdx.x >> 6;
#pragma unroll
  for (int i = 0; i < 16; ++i)
    t[ty * 16 + i][tx] = W[(size_t)(k0 + ty * 16 + i) * N + n0 + tx];
  __syncthreads();
#pragma unroll
  for (int i = 0; i < 16; ++i)
    Wt[(size_t)(n0 + ty * 16 + i) * 1024 + k0 + tx] = (bf16_t)t[tx][ty * 16 + i];
}

// Fused Q+KV projection: C = xb @ [WqT;WkvT]^T + bqkv, N=1152.
// y-tiles 0..7 -> Qb ; y-tile 8 -> KVb (cols 0-63 K, 64-127 V) + V^T side-write.
__global__ __launch_bounds__(256, 2)
void gemm_qkv(const bf16_t* __restrict__ A, const bf16_t* __restrict__ Bt,
              const float* __restrict__ bias, bf16_t* __restrict__ Qb,
              bf16_t* __restrict__ KVb, bf16_t* __restrict__ VtG, int M, int K) {
  __shared__ __align__(16) bf16_t As[128 * 32];
  __shared__ __align__(16) bf16_t Bs[128 * 32];
  const int tid = threadIdx.x;
  const int w = tid >> 6, l = tid & 63;
  const int l15 = l & 15, q = l >> 4;
  const int m0 = blockIdx.x * 128, n0 = blockIdx.y * 128;
  const int mw = (w >> 1) * 64, nw = (w & 1) * 64;
  f32x4 acc[4][4] = {};
  const int kb = (l & 3) * 8;
  int rA[2], rB[2];
#pragma unroll
  for (int i = 0; i < 2; ++i) {
    int row = (i * 4 + w) * 16 + (l >> 2);
    rA[i] = m0 + row;
    rB[i] = n0 + row;  // N=1152 = 9*128 exactly, no clamp needed
  }
  for (int k0 = 0; k0 < K; k0 += 32) {
#pragma unroll
    for (int i = 0; i < 2; ++i) {
      int sg = i * 4 + w;
      __builtin_amdgcn_global_load_lds(AS1(A + (size_t)rA[i] * K + k0 + kb),
                                       AS3(As + sg * 512), 16, 0, 0);
      __builtin_amdgcn_global_load_lds(AS1(Bt + (size_t)rB[i] * K + k0 + kb),
                                       AS3(Bs + sg * 512), 16, 0, 0);
    }
    __syncthreads();
    bf16x8 af[4], bfr[4];
#pragma unroll
    for (int mi = 0; mi < 4; ++mi)
      af[mi] = *(const bf16x8*)(As + (mw + mi * 16 + l15) * 32 + q * 8);
#pragma unroll
    for (int ni = 0; ni < 4; ++ni)
      bfr[ni] = *(const bf16x8*)(Bs + (nw + ni * 16 + l15) * 32 + q * 8);
#pragma unroll
    for (int mi = 0; mi < 4; ++mi)
#pragma unroll
      for (int ni = 0; ni < 4; ++ni)
        acc[mi][ni] = mfma16(af[mi], bfr[ni], acc[mi][ni]);
    __syncthreads();
  }
#pragma unroll
  for (int ni = 0; ni < 4; ++ni) {
    int col = n0 + nw + ni * 16 + l15;
    float bv = bias[col];
#pragma unroll
    for (int mi = 0; mi < 4; ++mi)
#pragma unroll
      for (int r = 0; r < 4; ++r) {
        int row = m0 + mw + mi * 16 + q * 4 + r;
        bf16_t v = (bf16_t)(acc[mi][ni][r] + bv);
        if (col < 1024) {
          Qb[(size_t)row * 1024 + col] = v;
        } else {
          int c2 = col - 1024;
          KVb[(size_t)row * 128 + c2] = v;
          if (c2 >= 64)
            VtG[(size_t)((row >> 11) * 64 + (c2 - 64)) * 2048 + (row & 2047)] = v;
        }
      }
  }
}

__global__ __launch_bounds__(256, 2)
void gemm_nt_bias_f32(const bf16_t* __restrict__ A, const bf16_t* __restrict__ Bt,
                      const float* __restrict__ bias, float* __restrict__ C,
                      int M, int N, int K) {
  __shared__ __align__(16) bf16_t As[128 * 32];
  __shared__ __align__(16) bf16_t Bs[128 * 32];
  const int tid = threadIdx.x;
  const int w = tid >> 6, l = tid & 63;
  const int l15 = l & 15, q = l >> 4;
  const int m0 = blockIdx.x * 128, n0 = blockIdx.y * 128;
  const int mw = (w >> 1) * 64, nw = (w & 1) * 64;
  f32x4 acc[4][4] = {};
  const int kb = (l & 3) * 8;
  int rA[2], rB[2];
#pragma unroll
  for (int i = 0; i < 2; ++i) {
    int row = (i * 4 + w) * 16 + (l >> 2);
    rA[i] = m0 + row;
    int rb = n0 + row; if (rb >= N) rb = N - 1;
    rB[i] = rb;
  }
  for (int k0 = 0; k0 < K; k0 += 32) {
#pragma unroll
    for (int i = 0; i < 2; ++i) {
      int sg = i * 4 + w;
      __builtin_amdgcn_global_load_lds(AS1(A + (size_t)rA[i] * K + k0 + kb),
                                       AS3(As + sg * 512), 16, 0, 0);
      __builtin_amdgcn_global_load_lds(AS1(Bt + (size_t)rB[i] * K + k0 + kb),
                                       AS3(Bs + sg * 512), 16, 0, 0);
    }
    __syncthreads();
    bf16x8 af[4], bfr[4];
#pragma unroll
    for (int mi = 0; mi < 4; ++mi)
      af[mi] = *(const bf16x8*)(As + (mw + mi * 16 + l15) * 32 + q * 8);
#pragma unroll
    for (int ni = 0; ni < 4; ++ni)
      bfr[ni] = *(const bf16x8*)(Bs + (nw + ni * 16 + l15) * 32 + q * 8);
#pragma unroll
    for (int mi = 0; mi < 4; ++mi)
#pragma unroll
      for (int ni = 0; ni < 4; ++ni)
        acc[mi][ni] = mfma16(af[mi], bfr[ni], acc[mi][ni]);
    __syncthreads();
  }
#pragma unroll
  for (int ni = 0; ni < 4; ++ni) {
    int col = n0 + nw + ni * 16 + l15;
    if (col >= N) continue;
    float bv = bias[col];
#pragma unroll
    for (int mi = 0; mi < 4; ++mi)
#pragma unroll
      for (int r = 0; r < 4; ++r) {
        int row = m0 + mw + mi * 16 + q * 4 + r;
        C[(size_t)row * N + col] = acc[mi][ni][r] + bv;
      }
  }
}

// ---- MQA flash v10: v9 + register double-buffered K prefetch (T14) ----
// v9 arithmetic: ~5.4K cy/step vs ~900 cy of issue work -> ~80% stall,
// dominated by K-fragment L2 latency sitting in front of QK^T each step
// (V is already issued early and consumed ~600cy later in PV -> hidden).
// Only 2 waves/SIMD exist (grid-capped), so hide K latency IN-WAVE:
// issue K(kt+1) into the alternate register set at the start of step kt.
// +32 VGPR; launch_bounds(128,2) keeps the 256-reg cap (v5/v7 64-clamp
// trap avoided). No barriers in the loop -> compiler's counted vmcnt
// preserves the pipeline (no m131 barrier-drain).
struct F8 { bf16x8 a0[4], a1[4]; };

__device__ __forceinline__ void load_kf(F8& f, const bf16_t* __restrict__ kbase,
                                        int kt, int l15, int q) {
  const bf16_t* kb = kbase + (size_t)kt * 64 * 128;  // K: cols 0-63 of KVb rows
#pragma unroll
  for (int mk = 0; mk < 4; ++mk) {
    const bf16_t* kr = kb + (mk * 16 + l15) * 128;
    f.a0[mk] = *(const bf16x8*)(kr + q * 8);
    f.a1[mk] = *(const bf16x8*)(kr + 32 + q * 8);
  }
}

__device__ __forceinline__ void load_vf(F8& f, const bf16_t* __restrict__ vbase,
                                        int kt, int l15, int q) {
#pragma unroll
  for (int md = 0; md < 4; ++md) {
    const bf16_t* vr = vbase + (size_t)(md * 16 + l15) * 2048 + kt * 64;
    f.a0[md] = *(const bf16x8*)(vr + q * 8);
    f.a1[md] = *(const bf16x8*)(vr + 32 + q * 8);
  }
}

template <bool DIAG>
__device__ __forceinline__ void attn_step(
    const F8& kf, const F8& vf, int l15, int q, bf16_t* __restrict__ ps,
    const bf16x8 (&qf0)[4], const bf16x8 (&qf1)[4],
    f32x4 (&o)[4][4], float (&rs)[4]) {
  const float c1 = 0.18033688f;  // log2(e)/8
  // S^T = K*Q^T in two mk-halves (bounds live s-registers)
#pragma unroll
  for (int mh = 0; mh < 2; ++mh) {
    f32x4 s2[2][4];
    __builtin_amdgcn_s_setprio(1);
#pragma unroll
    for (int mk2 = 0; mk2 < 2; ++mk2)
#pragma unroll
      for (int nq = 0; nq < 4; ++nq) {
        f32x4 t = {0.f, 0.f, 0.f, 0.f};
        t = mfma16(kf.a0[mh * 2 + mk2], qf0[nq], t);
        t = mfma16(kf.a1[mh * 2 + mk2], qf1[nq], t);
        s2[mk2][nq] = t;
      }
    __builtin_amdgcn_s_setprio(0);
#pragma unroll
    for (int nq = 0; nq < 4; ++nq)
#pragma unroll
      for (int mk2 = 0; mk2 < 2; ++mk2) {
        const int mk = mh * 2 + mk2;
        bf16x4 pk;
#pragma unroll
        for (int r = 0; r < 4; ++r) {
          float pv = __builtin_amdgcn_exp2f(s2[mk2][nq][r] * c1 - 16.0f);
          if (DIAG && (mk * 16 + q * 4 + r) > (nq * 16 + l15)) pv = 0.f;
          rs[nq] += pv;
          pk[r] = (bf16_t)pv;
        }
        *(bf16x4*)(ps + nq * 1152 + l15 * 72 + mk * 16 + q * 4) = pk;
      }
  }
  // O^T += V^T * P
#pragma unroll
  for (int nq = 0; nq < 4; ++nq) {
    bf16x8 pb0 = *(const bf16x8*)(ps + nq * 1152 + l15 * 72 + q * 8);
    bf16x8 pb1 = *(const bf16x8*)(ps + nq * 1152 + l15 * 72 + 32 + q * 8);
    __builtin_amdgcn_s_setprio(1);
#pragma unroll
    for (int md = 0; md < 4; ++md) {
      o[md][nq] = mfma16(vf.a0[md], pb0, o[md][nq]);
      o[md][nq] = mfma16(vf.a1[md], pb1, o[md][nq]);
    }
    __builtin_amdgcn_s_setprio(0);
  }
}

// Runs nondiag steps kt0..ktN-1, then (if ENDDIAG) the diag step at ktN.
// K fragments are register-double-buffered (kA/kB, statically named per
// rule #20); V uses a single set issued at step start (hidden under QK+SM).
template <bool ENDDIAG>
__device__ __forceinline__ void attn_run(
    const bf16_t* __restrict__ kbase, const bf16_t* __restrict__ vbase,
    int kt0, int ktN, int l15, int q, bf16_t* __restrict__ ps,
    const bf16x8 (&qf0)[4], const bf16x8 (&qf1)[4],
    f32x4 (&o)[4][4], float (&rs)[4]) {
  F8 kA, kB, vf;
  if (kt0 >= ktN) {  // diag-only range
    if (ENDDIAG) {
      load_kf(kA, kbase, ktN, l15, q);
      load_vf(vf, vbase, ktN, l15, q);
      attn_step<true>(kA, vf, l15, q, ps, qf0, qf1, o, rs);
    }
    return;
  }
  load_kf(kA, kbase, kt0, l15, q);
  int kt = kt0;
  while (true) {
    // A slot
    load_vf(vf, vbase, kt, l15, q);
    if ((kt + 1 < ktN) || ENDDIAG) load_kf(kB, kbase, kt + 1, l15, q);
    attn_step<false>(kA, vf, l15, q, ps, qf0, qf1, o, rs);
    ++kt;
    if (kt == ktN) {
      if (ENDDIAG) {
        load_vf(vf, vbase, kt, l15, q);
        attn_step<true>(kB, vf, l15, q, ps, qf0, qf1, o, rs);
      }
      return;
    }
    // B slot
    load_vf(vf, vbase, kt, l15, q);
    if ((kt + 1 < ktN) || ENDDIAG) load_kf(kA, kbase, kt + 1, l15, q);
    attn_step<false>(kB, vf, l15, q, ps, qf0, qf1, o, rs);
    ++kt;
    if (kt == ktN) {
      if (ENDDIAG) {
        load_vf(vf, vbase, kt, l15, q);
        attn_step<true>(kA, vf, l15, q, ps, qf0, qf1, o, rs);
      }
      return;
    }
  }
}

__device__ __forceinline__ void load_q(const bf16_t* __restrict__ Qb, int b, int h,
                                       int qt, int l15, int q,
                                       bf16x8 (&qf0)[4], bf16x8 (&qf1)[4]) {
#pragma unroll
  for (int nq = 0; nq < 4; ++nq) {
    const bf16_t* qp = Qb + (size_t)(b * 2048 + qt * 64 + nq * 16 + l15) * 1024 + h * 64 + q * 8;
    qf0[nq] = *(const bf16x8*)qp;
    qf1[nq] = *(const bf16x8*)(qp + 32);
  }
}

__device__ __forceinline__ void attn_finalize(bf16_t* __restrict__ AO, int b, int h,
                                              int qt, int l15, int q,
                                              f32x4 (&o)[4][4], float (&rs)[4]) {
#pragma unroll
  for (int nq = 0; nq < 4; ++nq) {
    rs[nq] += __shfl_xor(rs[nq], 16);
    rs[nq] += __shfl_xor(rs[nq], 32);
  }
  float inv[4];
#pragma unroll
  for (int nq = 0; nq < 4; ++nq) inv[nq] = 1.f / rs[nq];
#pragma unroll
  for (int md = 0; md < 4; ++md)
#pragma unroll
    for (int nq = 0; nq < 4; ++nq) {
      bf16x4 ov = {(bf16_t)(o[md][nq][0] * inv[nq]), (bf16_t)(o[md][nq][1] * inv[nq]),
                   (bf16_t)(o[md][nq][2] * inv[nq]), (bf16_t)(o[md][nq][3] * inv[nq])};
      *(bf16x4*)(AO + (size_t)(b * 2048 + qt * 64 + nq * 16 + l15) * 1024 +
                 h * 64 + md * 16 + q * 4) = ov;
    }
}

__global__ __launch_bounds__(128, 2)
void mqa_attn10(const bf16_t* __restrict__ Qb, const bf16_t* __restrict__ KVb,
                const bf16_t* __restrict__ VtG, bf16_t* __restrict__ AO) {
  __shared__ __align__(16) bf16_t Ps[2][4][16 * 72];  // 18 KB
  __shared__ __align__(16) float Oc[4096];            // 16 KB combine buffer
  __shared__ float RSc[256];                          // 1 KB
  const int u = blockIdx.x;
  const int b = u & 3;                 // one batch per XCD L2
  const int h = (u >> 2) & 15;
  const int p = (u >> 6) & 15;         // pair id; qt_h = 31-p, qt_l = p
  const int w = threadIdx.x >> 6, l = threadIdx.x & 63;
  const int l15 = l & 15, q = l >> 4;
  const int qt_h = 31 - p;
  bf16_t* ps = &Ps[w][0][0];
  const bf16_t* kbase = KVb + (size_t)b * 2048 * 128;
  const bf16_t* vbase = VtG + (size_t)b * 64 * 2048;

  bf16x8 qf0[4], qf1[4];
  f32x4 o[4][4] = {};
  float rs[4] = {0.f, 0.f, 0.f, 0.f};

  if (w == 0) {
    // first 17 steps of the heavy tile (diag included only when p==15)
    load_q(Qb, b, h, qt_h, l15, q, qf0, qf1);
    if (p == 15)
      attn_run<true>(kbase, vbase, 0, 16, l15, q, ps, qf0, qf1, o, rs);
    else
      attn_run<false>(kbase, vbase, 0, 17, l15, q, ps, qf0, qf1, o, rs);
    __syncthreads();  // wave1's partial is in Oc/RSc
#pragma unroll
    for (int md = 0; md < 4; ++md)
#pragma unroll
      for (int nq = 0; nq < 4; ++nq)
        o[md][nq] += *(const f32x4*)&Oc[((md * 4 + nq) * 64 + l) * 4];
#pragma unroll
    for (int nq = 0; nq < 4; ++nq) rs[nq] += RSc[l * 4 + nq];
    attn_finalize(AO, b, h, qt_h, l15, q, o, rs);
  } else {
    // light tile complete (p nondiag steps + diag), written directly
    load_q(Qb, b, h, p, l15, q, qf0, qf1);
    attn_run<true>(kbase, vbase, 0, p, l15, q, ps, qf0, qf1, o, rs);
    attn_finalize(AO, b, h, p, l15, q, o, rs);
    // heavy-tile tail [17, 31-p] incl diag (empty when p==15)
#pragma unroll
    for (int md = 0; md < 4; ++md)
#pragma unroll
      for (int nq = 0; nq < 4; ++nq) o[md][nq] = f32x4{0.f, 0.f, 0.f, 0.f};
    rs[0] = rs[1] = rs[2] = rs[3] = 0.f;
    if (p < 15) {
      load_q(Qb, b, h, qt_h, l15, q, qf0, qf1);
      attn_run<true>(kbase, vbase, 17, 31 - p, l15, q, ps, qf0, qf1, o, rs);
    }
#pragma unroll
    for (int md = 0; md < 4; ++md)
#pragma unroll
      for (int nq = 0; nq < 4; ++nq)
        *(f32x4*)&Oc[((md * 4 + nq) * 64 + l) * 4] = o[md][nq];
#pragma unroll
    for (int nq = 0; nq < 4; ++nq) RSc[l * 4 + nq] = rs[nq];
    __syncthreads();  // release partial to wave0
  }
}

extern "C" void kernel_launch(void* const* d_in, const int* in_sizes, int n_in,
                              void* d_out, int out_size, void* d_ws, size_t ws_size,
                              hipStream_t stream) {
  (void)in_sizes; (void)n_in; (void)out_size; (void)ws_size;
  const int BS = 8192;  // B*S
  const float* x  = (const float*)d_in[0];
  const float* Wq = (const float*)d_in[1];
  const float* bq = (const float*)d_in[2];
  const float* Wk = (const float*)d_in[3];
  const float* bk = (const float*)d_in[4];
  const float* Wv = (const float*)d_in[5];
  const float* bv = (const float*)d_in[6];
  const float* Wo = (const float*)d_in[7];
  const float* bo = (const float*)d_in[8];
  float* out = (float*)d_out;

  bf16_t* p = (bf16_t*)d_ws;
  bf16_t* WqT  = p; p += 1024 * 1024;  // rows 0-1023 of fused Bt
  bf16_t* WkvT = p; p += 128 * 1024;   // rows 1024-1151 (contiguous after WqT)
  bf16_t* WoT  = p; p += 1024 * 1024;
  bf16_t* xb   = p; p += (size_t)BS * 1024;
  bf16_t* Qb   = p; p += (size_t)BS * 1024;
  bf16_t* KVb  = p; p += (size_t)BS * 128;   // cols 0-63 = K, 64-127 = V
  bf16_t* VtG  = p; p += (size_t)4 * 64 * 2048;  // own buffer (WqT live in fused gemm)
  float*  bqkv = (float*)p; p += 2304;       // 1152 f32
  bf16_t* AO  = xb;   // x dead after projections

  // 4 launches: prep, fused QKV gemm (+V^T side-write), attn, O gemm.
  prep<<<dim3(546 + 8192), 256, 0, stream>>>(x, Wq, Wk, Wv, Wo, bq, bk, bv,
                                             xb, WqT, WkvT, WoT, bqkv);

  gemm_qkv<<<dim3(BS / 128, 9), 256, 0, stream>>>(xb, WqT, bqkv, Qb, KVb, VtG, BS, 1024);

  mqa_attn10<<<dim3(1024), 128, 0, stream>>>(Qb, KVb, VtG, AO);

  gemm_nt_bias_f32<<<dim3(BS / 128, 8), 256, 0, stream>>>(AO, WoT, bo, out, BS, 1024, 1024);
}

// Round 8
// 236.979 us; speedup vs baseline: 1.1482x; 1.1482x over previous
//
#include <hip/hip_runtime.h>
#include <hip/hip_bf16.h>

typedef __bf16 bf16_t;
typedef __bf16 bf16x4 __attribute__((ext_vector_type(4)));
typedef __bf16 bf16x8 __attribute__((ext_vector_type(8)));
typedef float f32x4 __attribute__((ext_vector_type(4)));

#define AS1(p) ((const __attribute__((address_space(1))) void*)(p))
#define AS3(p) ((__attribute__((address_space(3))) void*)(p))

__device__ __forceinline__ f32x4 mfma16(bf16x8 a, bf16x8 b, f32x4 c) {
  return __builtin_amdgcn_mfma_f32_16x16x32_bf16(a, b, c, 0, 0, 0);
}

// ---- fused prep: x cast + 4 weight transposes + combined bias build ----
__global__ void prep(const float* __restrict__ x, const float* __restrict__ Wq,
                     const float* __restrict__ Wk, const float* __restrict__ Wv,
                     const float* __restrict__ Wo, const float* __restrict__ bq,
                     const float* __restrict__ bk, const float* __restrict__ bv,
                     bf16_t* __restrict__ xb, bf16_t* __restrict__ WqT,
                     bf16_t* __restrict__ WkvT, bf16_t* __restrict__ WoT,
                     float* __restrict__ bqkv) {
  const int u = blockIdx.x;
  if (u >= 546) {  // x cast: 8192*1024 f32 -> bf16, 4/lane
    int i = ((u - 546) * 256 + threadIdx.x) * 4;
    float4 v = *(const float4*)(x + i);
    bf16x4 o = {(bf16_t)v.x, (bf16_t)v.y, (bf16_t)v.z, (bf16_t)v.w};
    *(bf16x4*)(xb + i) = o;
    return;
  }
  if (u == 544) {  // bq copy (1024 f32)
    int i = threadIdx.x * 4;
    *(float4*)(bqkv + i) = *(const float4*)(bq + i);
    return;
  }
  if (u == 545) {  // bk/bv pack
    if (threadIdx.x < 128)
      bqkv[1024 + threadIdx.x] =
          (threadIdx.x < 64) ? bk[threadIdx.x] : bv[threadIdx.x - 64];
    return;
  }
  const float* W; bf16_t* Wt; int N, bx, by;
  if (u < 256)      { W = Wq; Wt = WqT;              N = 1024; bx = u & 15;         by = u >> 4; }
  else if (u < 272) { W = Wk; Wt = WkvT;             N = 64;   bx = 0;              by = u - 256; }
  else if (u < 288) { W = Wv; Wt = WkvT + 64 * 1024; N = 64;   bx = 0;              by = u - 272; }
  else              { W = Wo; Wt = WoT;              N = 1024; bx = (u - 288) & 15; by = (u - 288) >> 4; }
  __shared__ float t[64][65];
  const int n0 = bx * 64, k0 = by * 64;
  const int tx = threadIdx.x & 63, ty = threadIdx.x >> 6;
#pragma unroll
  for (int i = 0; i < 16; ++i)
    t[ty * 16 + i][tx] = W[(size_t)(k0 + ty * 16 + i) * N + n0 + tx];
  __syncthreads();
#pragma unroll
  for (int i = 0; i < 16; ++i)
    Wt[(size_t)(n0 + ty * 16 + i) * 1024 + k0 + tx] = (bf16_t)t[tx][ty * 16 + i];
}

// Fused Q+KV projection: C = xb @ [WqT;WkvT]^T + bqkv, N=1152.
// N-FASTEST grid (grid.x = n-tile): consecutive blocks share the 256KB
// A-panel (L2/L1-hot); full B (2.25MB) stays L2-resident across M-tiles.
__global__ __launch_bounds__(256, 2)
void gemm_qkv(const bf16_t* __restrict__ A, const bf16_t* __restrict__ Bt,
              const float* __restrict__ bias, bf16_t* __restrict__ Qb,
              bf16_t* __restrict__ KVb, bf16_t* __restrict__ VtG, int M, int K) {
  __shared__ __align__(16) bf16_t As[128 * 32];
  __shared__ __align__(16) bf16_t Bs[128 * 32];
  const int tid = threadIdx.x;
  const int w = tid >> 6, l = tid & 63;
  const int l15 = l & 15, q = l >> 4;
  const int m0 = blockIdx.y * 128, n0 = blockIdx.x * 128;
  const int mw = (w >> 1) * 64, nw = (w & 1) * 64;
  f32x4 acc[4][4] = {};
  const int kb = (l & 3) * 8;
  int rA[2], rB[2];
#pragma unroll
  for (int i = 0; i < 2; ++i) {
    int row = (i * 4 + w) * 16 + (l >> 2);
    rA[i] = m0 + row;
    rB[i] = n0 + row;  // N=1152 = 9*128 exactly
  }
  for (int k0 = 0; k0 < K; k0 += 32) {
#pragma unroll
    for (int i = 0; i < 2; ++i) {
      int sg = i * 4 + w;
      __builtin_amdgcn_global_load_lds(AS1(A + (size_t)rA[i] * K + k0 + kb),
                                       AS3(As + sg * 512), 16, 0, 0);
      __builtin_amdgcn_global_load_lds(AS1(Bt + (size_t)rB[i] * K + k0 + kb),
                                       AS3(Bs + sg * 512), 16, 0, 0);
    }
    __syncthreads();
    bf16x8 af[4], bfr[4];
#pragma unroll
    for (int mi = 0; mi < 4; ++mi)
      af[mi] = *(const bf16x8*)(As + (mw + mi * 16 + l15) * 32 + q * 8);
#pragma unroll
    for (int ni = 0; ni < 4; ++ni)
      bfr[ni] = *(const bf16x8*)(Bs + (nw + ni * 16 + l15) * 32 + q * 8);
#pragma unroll
    for (int mi = 0; mi < 4; ++mi)
#pragma unroll
      for (int ni = 0; ni < 4; ++ni)
        acc[mi][ni] = mfma16(af[mi], bfr[ni], acc[mi][ni]);
    __syncthreads();
  }
#pragma unroll
  for (int ni = 0; ni < 4; ++ni) {
    int col = n0 + nw + ni * 16 + l15;
    float bv = bias[col];
#pragma unroll
    for (int mi = 0; mi < 4; ++mi)
#pragma unroll
      for (int r = 0; r < 4; ++r) {
        int row = m0 + mw + mi * 16 + q * 4 + r;
        bf16_t v = (bf16_t)(acc[mi][ni][r] + bv);
        if (col < 1024) {
          Qb[(size_t)row * 1024 + col] = v;
        } else {
          int c2 = col - 1024;
          KVb[(size_t)row * 128 + c2] = v;
          if (c2 >= 64)
            VtG[(size_t)((row >> 11) * 64 + (c2 - 64)) * 2048 + (row & 2047)] = v;
        }
      }
  }
}

// O-projection GEMM, N-fastest grid (same A-panel-reuse rationale).
__global__ __launch_bounds__(256, 2)
void gemm_nt_bias_f32(const bf16_t* __restrict__ A, const bf16_t* __restrict__ Bt,
                      const float* __restrict__ bias, float* __restrict__ C,
                      int M, int N, int K) {
  __shared__ __align__(16) bf16_t As[128 * 32];
  __shared__ __align__(16) bf16_t Bs[128 * 32];
  const int tid = threadIdx.x;
  const int w = tid >> 6, l = tid & 63;
  const int l15 = l & 15, q = l >> 4;
  const int m0 = blockIdx.y * 128, n0 = blockIdx.x * 128;
  const int mw = (w >> 1) * 64, nw = (w & 1) * 64;
  f32x4 acc[4][4] = {};
  const int kb = (l & 3) * 8;
  int rA[2], rB[2];
#pragma unroll
  for (int i = 0; i < 2; ++i) {
    int row = (i * 4 + w) * 16 + (l >> 2);
    rA[i] = m0 + row;
    int rb = n0 + row; if (rb >= N) rb = N - 1;
    rB[i] = rb;
  }
  for (int k0 = 0; k0 < K; k0 += 32) {
#pragma unroll
    for (int i = 0; i < 2; ++i) {
      int sg = i * 4 + w;
      __builtin_amdgcn_global_load_lds(AS1(A + (size_t)rA[i] * K + k0 + kb),
                                       AS3(As + sg * 512), 16, 0, 0);
      __builtin_amdgcn_global_load_lds(AS1(Bt + (size_t)rB[i] * K + k0 + kb),
                                       AS3(Bs + sg * 512), 16, 0, 0);
    }
    __syncthreads();
    bf16x8 af[4], bfr[4];
#pragma unroll
    for (int mi = 0; mi < 4; ++mi)
      af[mi] = *(const bf16x8*)(As + (mw + mi * 16 + l15) * 32 + q * 8);
#pragma unroll
    for (int ni = 0; ni < 4; ++ni)
      bfr[ni] = *(const bf16x8*)(Bs + (nw + ni * 16 + l15) * 32 + q * 8);
#pragma unroll
    for (int mi = 0; mi < 4; ++mi)
#pragma unroll
      for (int ni = 0; ni < 4; ++ni)
        acc[mi][ni] = mfma16(af[mi], bfr[ni], acc[mi][ni]);
    __syncthreads();
  }
#pragma unroll
  for (int ni = 0; ni < 4; ++ni) {
    int col = n0 + nw + ni * 16 + l15;
    if (col >= N) continue;
    float bv = bias[col];
#pragma unroll
    for (int mi = 0; mi < 4; ++mi)
#pragma unroll
      for (int r = 0; r < 4; ++r) {
        int row = m0 + mw + mi * 16 + q * 4 + r;
        C[(size_t)row * N + col] = acc[mi][ni][r] + bv;
      }
  }
}

// ---- MQA flash v11 = v9 attn (proven 76.5us, VGPR 112) on the v10 pipeline ----
// v10 post-mortem: allocator never exceeds 128 VGPR for this kernel shape
// (observed ceiling across 7 rounds); the K register-double-buffer's ~230
// live values spilled (WRITE 128MB). Register-budget lever is CLOSED; this
// is the proven no-spill inner loop.
__device__ __forceinline__ void load_q(const bf16_t* __restrict__ Qb, int b, int h,
                                       int qt, int l15, int q,
                                       bf16x8 (&qf0)[4], bf16x8 (&qf1)[4]) {
#pragma unroll
  for (int nq = 0; nq < 4; ++nq) {
    const bf16_t* qp = Qb + (size_t)(b * 2048 + qt * 64 + nq * 16 + l15) * 1024 + h * 64 + q * 8;
    qf0[nq] = *(const bf16x8*)qp;
    qf1[nq] = *(const bf16x8*)(qp + 32);
  }
}

template <bool DIAG>
__device__ __forceinline__ void attn_step(
    const bf16_t* __restrict__ kbase, const bf16_t* __restrict__ vbase, int kt,
    int l15, int q, bf16_t* __restrict__ ps,
    const bf16x8 (&qf0)[4], const bf16x8 (&qf1)[4],
    f32x4 (&o)[4][4], float (&rs)[4]) {
  const float c1 = 0.18033688f;  // log2(e)/8
  const bf16_t* kb = kbase + (size_t)kt * 64 * 128;  // K: cols 0-63 of KVb rows
  bf16x8 ka0[4], ka1[4];
#pragma unroll
  for (int mk = 0; mk < 4; ++mk) {
    const bf16_t* kr = kb + (mk * 16 + l15) * 128;
    ka0[mk] = *(const bf16x8*)(kr + q * 8);
    ka1[mk] = *(const bf16x8*)(kr + 32 + q * 8);
  }
  bf16x8 va0[4], va1[4];
#pragma unroll
  for (int md = 0; md < 4; ++md) {
    const bf16_t* vr = vbase + (size_t)(md * 16 + l15) * 2048 + kt * 64;
    va0[md] = *(const bf16x8*)(vr + q * 8);
    va1[md] = *(const bf16x8*)(vr + 32 + q * 8);
  }
  // S^T = K*Q^T in two mk-halves (bounds live s-registers)
#pragma unroll
  for (int mh = 0; mh < 2; ++mh) {
    f32x4 s2[2][4];
    __builtin_amdgcn_s_setprio(1);
#pragma unroll
    for (int mk2 = 0; mk2 < 2; ++mk2)
#pragma unroll
      for (int nq = 0; nq < 4; ++nq) {
        f32x4 t = {0.f, 0.f, 0.f, 0.f};
        t = mfma16(ka0[mh * 2 + mk2], qf0[nq], t);
        t = mfma16(ka1[mh * 2 + mk2], qf1[nq], t);
        s2[mk2][nq] = t;
      }
    __builtin_amdgcn_s_setprio(0);
#pragma unroll
    for (int nq = 0; nq < 4; ++nq)
#pragma unroll
      for (int mk2 = 0; mk2 < 2; ++mk2) {
        const int mk = mh * 2 + mk2;
        bf16x4 pk;
#pragma unroll
        for (int r = 0; r < 4; ++r) {
          float pv = __builtin_amdgcn_exp2f(s2[mk2][nq][r] * c1 - 16.0f);
          if (DIAG && (mk * 16 + q * 4 + r) > (nq * 16 + l15)) pv = 0.f;
          rs[nq] += pv;
          pk[r] = (bf16_t)pv;
        }
        *(bf16x4*)(ps + nq * 1152 + l15 * 72 + mk * 16 + q * 4) = pk;
      }
  }
  // O^T += V^T * P
#pragma unroll
  for (int nq = 0; nq < 4; ++nq) {
    bf16x8 pb0 = *(const bf16x8*)(ps + nq * 1152 + l15 * 72 + q * 8);
    bf16x8 pb1 = *(const bf16x8*)(ps + nq * 1152 + l15 * 72 + 32 + q * 8);
    __builtin_amdgcn_s_setprio(1);
#pragma unroll
    for (int md = 0; md < 4; ++md) {
      o[md][nq] = mfma16(va0[md], pb0, o[md][nq]);
      o[md][nq] = mfma16(va1[md], pb1, o[md][nq]);
    }
    __builtin_amdgcn_s_setprio(0);
  }
}

__device__ __forceinline__ void attn_finalize(bf16_t* __restrict__ AO, int b, int h,
                                              int qt, int l15, int q,
                                              f32x4 (&o)[4][4], float (&rs)[4]) {
#pragma unroll
  for (int nq = 0; nq < 4; ++nq) {
    rs[nq] += __shfl_xor(rs[nq], 16);
    rs[nq] += __shfl_xor(rs[nq], 32);
  }
  float inv[4];
#pragma unroll
  for (int nq = 0; nq < 4; ++nq) inv[nq] = 1.f / rs[nq];
#pragma unroll
  for (int md = 0; md < 4; ++md)
#pragma unroll
    for (int nq = 0; nq < 4; ++nq) {
      bf16x4 ov = {(bf16_t)(o[md][nq][0] * inv[nq]), (bf16_t)(o[md][nq][1] * inv[nq]),
                   (bf16_t)(o[md][nq][2] * inv[nq]), (bf16_t)(o[md][nq][3] * inv[nq])};
      *(bf16x4*)(AO + (size_t)(b * 2048 + qt * 64 + nq * 16 + l15) * 1024 +
                 h * 64 + md * 16 + q * 4) = ov;
    }
}

__global__ __launch_bounds__(128, 2)
void mqa_attn9(const bf16_t* __restrict__ Qb, const bf16_t* __restrict__ KVb,
               const bf16_t* __restrict__ VtG, bf16_t* __restrict__ AO) {
  __shared__ __align__(16) bf16_t Ps[2][4][16 * 72];  // 18 KB
  __shared__ __align__(16) float Oc[4096];            // 16 KB combine buffer
  __shared__ float RSc[256];                          // 1 KB
  const int u = blockIdx.x;
  const int b = u & 3;                 // one batch per XCD L2
  const int h = (u >> 2) & 15;
  const int p = (u >> 6) & 15;         // pair id; qt_h = 31-p, qt_l = p
  const int w = threadIdx.x >> 6, l = threadIdx.x & 63;
  const int l15 = l & 15, q = l >> 4;
  const int qt_h = 31 - p;
  bf16_t* ps = &Ps[w][0][0];
  const bf16_t* kbase = KVb + (size_t)b * 2048 * 128;
  const bf16_t* vbase = VtG + (size_t)b * 64 * 2048;

  bf16x8 qf0[4], qf1[4];
  f32x4 o[4][4] = {};
  float rs[4] = {0.f, 0.f, 0.f, 0.f};

  if (w == 0) {
    // first 17 steps of the heavy tile (diag included only when p==15)
    load_q(Qb, b, h, qt_h, l15, q, qf0, qf1);
    const int e = (p == 15) ? 16 : 17;
    for (int kt = 0; kt < e; ++kt)
      attn_step<false>(kbase, vbase, kt, l15, q, ps, qf0, qf1, o, rs);
    if (p == 15)
      attn_step<true>(kbase, vbase, 16, l15, q, ps, qf0, qf1, o, rs);
    __syncthreads();  // wave1's partial is in Oc/RSc
#pragma unroll
    for (int md = 0; md < 4; ++md)
#pragma unroll
      for (int nq = 0; nq < 4; ++nq)
        o[md][nq] += *(const f32x4*)&Oc[((md * 4 + nq) * 64 + l) * 4];
#pragma unroll
    for (int nq = 0; nq < 4; ++nq) rs[nq] += RSc[l * 4 + nq];
    attn_finalize(AO, b, h, qt_h, l15, q, o, rs);
  } else {
    // light tile complete (p steps + diag), written directly
    load_q(Qb, b, h, p, l15, q, qf0, qf1);
    for (int kt = 0; kt < p; ++kt)
      attn_step<false>(kbase, vbase, kt, l15, q, ps, qf0, qf1, o, rs);
    attn_step<true>(kbase, vbase, p, l15, q, ps, qf0, qf1, o, rs);
    attn_finalize(AO, b, h, p, l15, q, o, rs);
    // heavy-tile tail [17, 31-p] incl diag (empty when p==15)
#pragma unroll
    for (int md = 0; md < 4; ++md)
#pragma unroll
      for (int nq = 0; nq < 4; ++nq) o[md][nq] = f32x4{0.f, 0.f, 0.f, 0.f};
    rs[0] = rs[1] = rs[2] = rs[3] = 0.f;
    if (p < 15) {
      load_q(Qb, b, h, qt_h, l15, q, qf0, qf1);
      for (int kt = 17; kt < 31 - p; ++kt)
        attn_step<false>(kbase, vbase, kt, l15, q, ps, qf0, qf1, o, rs);
      attn_step<true>(kbase, vbase, 31 - p, l15, q, ps, qf0, qf1, o, rs);
    }
#pragma unroll
    for (int md = 0; md < 4; ++md)
#pragma unroll
      for (int nq = 0; nq < 4; ++nq)
        *(f32x4*)&Oc[((md * 4 + nq) * 64 + l) * 4] = o[md][nq];
#pragma unroll
    for (int nq = 0; nq < 4; ++nq) RSc[l * 4 + nq] = rs[nq];
    __syncthreads();  // release partial to wave0
  }
}

extern "C" void kernel_launch(void* const* d_in, const int* in_sizes, int n_in,
                              void* d_out, int out_size, void* d_ws, size_t ws_size,
                              hipStream_t stream) {
  (void)in_sizes; (void)n_in; (void)out_size; (void)ws_size;
  const int BS = 8192;  // B*S
  const float* x  = (const float*)d_in[0];
  const float* Wq = (const float*)d_in[1];
  const float* bq = (const float*)d_in[2];
  const float* Wk = (const float*)d_in[3];
  const float* bk = (const float*)d_in[4];
  const float* Wv = (const float*)d_in[5];
  const float* bv = (const float*)d_in[6];
  const float* Wo = (const float*)d_in[7];
  const float* bo = (const float*)d_in[8];
  float* out = (float*)d_out;

  bf16_t* p = (bf16_t*)d_ws;
  bf16_t* WqT  = p; p += 1024 * 1024;  // rows 0-1023 of fused Bt
  bf16_t* WkvT = p; p += 128 * 1024;   // rows 1024-1151 (contiguous after WqT)
  bf16_t* WoT  = p; p += 1024 * 1024;
  bf16_t* xb   = p; p += (size_t)BS * 1024;
  bf16_t* Qb   = p; p += (size_t)BS * 1024;
  bf16_t* KVb  = p; p += (size_t)BS * 128;   // cols 0-63 = K, 64-127 = V
  bf16_t* VtG  = p; p += (size_t)4 * 64 * 2048;
  float*  bqkv = (float*)p; p += 2304;       // 1152 f32
  bf16_t* AO  = xb;   // x dead after projections

  // 4 launches: prep, fused QKV gemm (+V^T side-write), attn, O gemm.
  prep<<<dim3(546 + 8192), 256, 0, stream>>>(x, Wq, Wk, Wv, Wo, bq, bk, bv,
                                             xb, WqT, WkvT, WoT, bqkv);

  gemm_qkv<<<dim3(9, BS / 128), 256, 0, stream>>>(xb, WqT, bqkv, Qb, KVb, VtG, BS, 1024);

  mqa_attn9<<<dim3(1024), 128, 0, stream>>>(Qb, KVb, VtG, AO);

  gemm_nt_bias_f32<<<dim3(8, BS / 128), 256, 0, stream>>>(AO, WoT, bo, out, BS, 1024, 1024);
}

// Round 10
// 232.912 us; speedup vs baseline: 1.1683x; 1.0175x over previous
//
#include <hip/hip_runtime.h>
#include <hip/hip_bf16.h>

typedef __bf16 bf16_t;
typedef __bf16 bf16x4 __attribute__((ext_vector_type(4)));
typedef __bf16 bf16x8 __attribute__((ext_vector_type(8)));
typedef float f32x4 __attribute__((ext_vector_type(4)));

#define AS1(p) ((const __attribute__((address_space(1))) void*)(p))
#define AS3(p) ((__attribute__((address_space(3))) void*)(p))

__device__ __forceinline__ f32x4 mfma16(bf16x8 a, bf16x8 b, f32x4 c) {
  return __builtin_amdgcn_mfma_f32_16x16x32_bf16(a, b, c, 0, 0, 0);
}

// ---- fused prep: x cast + 4 weight transposes + combined bias build ----
__global__ void prep(const float* __restrict__ x, const float* __restrict__ Wq,
                     const float* __restrict__ Wk, const float* __restrict__ Wv,
                     const float* __restrict__ Wo, const float* __restrict__ bq,
                     const float* __restrict__ bk, const float* __restrict__ bv,
                     bf16_t* __restrict__ xb, bf16_t* __restrict__ WqT,
                     bf16_t* __restrict__ WkvT, bf16_t* __restrict__ WoT,
                     float* __restrict__ bqkv) {
  const int u = blockIdx.x;
  if (u >= 546) {  // x cast: 8192*1024 f32 -> bf16, 4/lane
    int i = ((u - 546) * 256 + threadIdx.x) * 4;
    float4 v = *(const float4*)(x + i);
    bf16x4 o = {(bf16_t)v.x, (bf16_t)v.y, (bf16_t)v.z, (bf16_t)v.w};
    *(bf16x4*)(xb + i) = o;
    return;
  }
  if (u == 544) {  // bq copy (1024 f32)
    int i = threadIdx.x * 4;
    *(float4*)(bqkv + i) = *(const float4*)(bq + i);
    return;
  }
  if (u == 545) {  // bk/bv pack
    if (threadIdx.x < 128)
      bqkv[1024 + threadIdx.x] =
          (threadIdx.x < 64) ? bk[threadIdx.x] : bv[threadIdx.x - 64];
    return;
  }
  const float* W; bf16_t* Wt; int N, bx, by;
  if (u < 256)      { W = Wq; Wt = WqT;              N = 1024; bx = u & 15;         by = u >> 4; }
  else if (u < 272) { W = Wk; Wt = WkvT;             N = 64;   bx = 0;              by = u - 256; }
  else if (u < 288) { W = Wv; Wt = WkvT + 64 * 1024; N = 64;   bx = 0;              by = u - 272; }
  else              { W = Wo; Wt = WoT;              N = 1024; bx = (u - 288) & 15; by = (u - 288) >> 4; }
  __shared__ float t[64][65];
  const int n0 = bx * 64, k0 = by * 64;
  const int tx = threadIdx.x & 63, ty = threadIdx.x >> 6;
#pragma unroll
  for (int i = 0; i < 16; ++i)
    t[ty * 16 + i][tx] = W[(size_t)(k0 + ty * 16 + i) * N + n0 + tx];
  __syncthreads();
#pragma unroll
  for (int i = 0; i < 16; ++i)
    Wt[(size_t)(n0 + ty * 16 + i) * 1024 + k0 + tx] = (bf16_t)t[tx][ty * 16 + i];
}

// Fused Q+KV projection: C = xb @ [WqT;WkvT]^T + bqkv, N=1152. M-fastest grid
// (v11 post-mortem: N-fastest swap measured ~11us WORSE; reverted to v10 order).
__global__ __launch_bounds__(256, 2)
void gemm_qkv(const bf16_t* __restrict__ A, const bf16_t* __restrict__ Bt,
              const float* __restrict__ bias, bf16_t* __restrict__ Qb,
              bf16_t* __restrict__ KVb, bf16_t* __restrict__ VtG, int M, int K) {
  __shared__ __align__(16) bf16_t As[128 * 32];
  __shared__ __align__(16) bf16_t Bs[128 * 32];
  const int tid = threadIdx.x;
  const int w = tid >> 6, l = tid & 63;
  const int l15 = l & 15, q = l >> 4;
  const int m0 = blockIdx.x * 128, n0 = blockIdx.y * 128;
  const int mw = (w >> 1) * 64, nw = (w & 1) * 64;
  f32x4 acc[4][4] = {};
  const int kb = (l & 3) * 8;
  int rA[2], rB[2];
#pragma unroll
  for (int i = 0; i < 2; ++i) {
    int row = (i * 4 + w) * 16 + (l >> 2);
    rA[i] = m0 + row;
    rB[i] = n0 + row;  // N=1152 = 9*128 exactly
  }
  for (int k0 = 0; k0 < K; k0 += 32) {
#pragma unroll
    for (int i = 0; i < 2; ++i) {
      int sg = i * 4 + w;
      __builtin_amdgcn_global_load_lds(AS1(A + (size_t)rA[i] * K + k0 + kb),
                                       AS3(As + sg * 512), 16, 0, 0);
      __builtin_amdgcn_global_load_lds(AS1(Bt + (size_t)rB[i] * K + k0 + kb),
                                       AS3(Bs + sg * 512), 16, 0, 0);
    }
    __syncthreads();
    bf16x8 af[4], bfr[4];
#pragma unroll
    for (int mi = 0; mi < 4; ++mi)
      af[mi] = *(const bf16x8*)(As + (mw + mi * 16 + l15) * 32 + q * 8);
#pragma unroll
    for (int ni = 0; ni < 4; ++ni)
      bfr[ni] = *(const bf16x8*)(Bs + (nw + ni * 16 + l15) * 32 + q * 8);
#pragma unroll
    for (int mi = 0; mi < 4; ++mi)
#pragma unroll
      for (int ni = 0; ni < 4; ++ni)
        acc[mi][ni] = mfma16(af[mi], bfr[ni], acc[mi][ni]);
    __syncthreads();
  }
#pragma unroll
  for (int ni = 0; ni < 4; ++ni) {
    int col = n0 + nw + ni * 16 + l15;
    float bv = bias[col];
#pragma unroll
    for (int mi = 0; mi < 4; ++mi)
#pragma unroll
      for (int r = 0; r < 4; ++r) {
        int row = m0 + mw + mi * 16 + q * 4 + r;
        bf16_t v = (bf16_t)(acc[mi][ni][r] + bv);
        if (col < 1024) {
          Qb[(size_t)row * 1024 + col] = v;
        } else {
          int c2 = col - 1024;
          KVb[(size_t)row * 128 + c2] = v;
          if (c2 >= 64)
            VtG[(size_t)((row >> 11) * 64 + (c2 - 64)) * 2048 + (row & 2047)] = v;
        }
      }
  }
}

__global__ __launch_bounds__(256, 2)
void gemm_nt_bias_f32(const bf16_t* __restrict__ A, const bf16_t* __restrict__ Bt,
                      const float* __restrict__ bias, float* __restrict__ C,
                      int M, int N, int K) {
  __shared__ __align__(16) bf16_t As[128 * 32];
  __shared__ __align__(16) bf16_t Bs[128 * 32];
  const int tid = threadIdx.x;
  const int w = tid >> 6, l = tid & 63;
  const int l15 = l & 15, q = l >> 4;
  const int m0 = blockIdx.x * 128, n0 = blockIdx.y * 128;
  const int mw = (w >> 1) * 64, nw = (w & 1) * 64;
  f32x4 acc[4][4] = {};
  const int kb = (l & 3) * 8;
  int rA[2], rB[2];
#pragma unroll
  for (int i = 0; i < 2; ++i) {
    int row = (i * 4 + w) * 16 + (l >> 2);
    rA[i] = m0 + row;
    int rb = n0 + row; if (rb >= N) rb = N - 1;
    rB[i] = rb;
  }
  for (int k0 = 0; k0 < K; k0 += 32) {
#pragma unroll
    for (int i = 0; i < 2; ++i) {
      int sg = i * 4 + w;
      __builtin_amdgcn_global_load_lds(AS1(A + (size_t)rA[i] * K + k0 + kb),
                                       AS3(As + sg * 512), 16, 0, 0);
      __builtin_amdgcn_global_load_lds(AS1(Bt + (size_t)rB[i] * K + k0 + kb),
                                       AS3(Bs + sg * 512), 16, 0, 0);
    }
    __syncthreads();
    bf16x8 af[4], bfr[4];
#pragma unroll
    for (int mi = 0; mi < 4; ++mi)
      af[mi] = *(const bf16x8*)(As + (mw + mi * 16 + l15) * 32 + q * 8);
#pragma unroll
    for (int ni = 0; ni < 4; ++ni)
      bfr[ni] = *(const bf16x8*)(Bs + (nw + ni * 16 + l15) * 32 + q * 8);
#pragma unroll
    for (int mi = 0; mi < 4; ++mi)
#pragma unroll
      for (int ni = 0; ni < 4; ++ni)
        acc[mi][ni] = mfma16(af[mi], bfr[ni], acc[mi][ni]);
    __syncthreads();
  }
#pragma unroll
  for (int ni = 0; ni < 4; ++ni) {
    int col = n0 + nw + ni * 16 + l15;
    if (col >= N) continue;
    float bv = bias[col];
#pragma unroll
    for (int mi = 0; mi < 4; ++mi)
#pragma unroll
      for (int r = 0; r < 4; ++r) {
        int row = m0 + mw + mi * 16 + q * 4 + r;
        C[(size_t)row * N + col] = acc[mi][ni][r] + bv;
      }
  }
}

// ---- MQA flash v12: 4-wave kt-split, 16 waves/CU ----
// v9 was grid-capped at 8 waves/CU (2048 waves) with 43% issue util -- the
// stall is latency, the cure is TLP, and v8/v10 closed the other routes
// (fewer queries/wave loses arithmetic intensity; >128 VGPR spills).
// Fixed-shift softmax is LINEAR in kt -> kt ranges split and partials add.
// Block = one (qt,h,b) tile, 4 waves: wave w takes kt==w (mod 4) + diag if
// qt==w (mod 4). Same per-wave live set as v9 (VGPR ~112, no spill).
// Combine through the DEAD Ps buffer (regions A=Ps[0..1], B=Ps[2..3], each
// 18.4KB >= 17.4KB of f32 partials) in 2 pairwise rounds + 4 barriers.
// LDS 36.9KB -> 4 blocks/CU x 4 waves = 16 waves/CU (2x v9). Heavy-first.
__device__ __forceinline__ void load_q(const bf16_t* __restrict__ Qb, int b, int h,
                                       int qt, int l15, int q,
                                       bf16x8 (&qf0)[4], bf16x8 (&qf1)[4]) {
#pragma unroll
  for (int nq = 0; nq < 4; ++nq) {
    const bf16_t* qp = Qb + (size_t)(b * 2048 + qt * 64 + nq * 16 + l15) * 1024 + h * 64 + q * 8;
    qf0[nq] = *(const bf16x8*)qp;
    qf1[nq] = *(const bf16x8*)(qp + 32);
  }
}

template <bool DIAG>
__device__ __forceinline__ void attn_step(
    const bf16_t* __restrict__ kbase, const bf16_t* __restrict__ vbase, int kt,
    int l15, int q, bf16_t* __restrict__ ps,
    const bf16x8 (&qf0)[4], const bf16x8 (&qf1)[4],
    f32x4 (&o)[4][4], float (&rs)[4]) {
  const float c1 = 0.18033688f;  // log2(e)/8
  const bf16_t* kb = kbase + (size_t)kt * 64 * 128;  // K: cols 0-63 of KVb rows
  bf16x8 ka0[4], ka1[4];
#pragma unroll
  for (int mk = 0; mk < 4; ++mk) {
    const bf16_t* kr = kb + (mk * 16 + l15) * 128;
    ka0[mk] = *(const bf16x8*)(kr + q * 8);
    ka1[mk] = *(const bf16x8*)(kr + 32 + q * 8);
  }
  bf16x8 va0[4], va1[4];
#pragma unroll
  for (int md = 0; md < 4; ++md) {
    const bf16_t* vr = vbase + (size_t)(md * 16 + l15) * 2048 + kt * 64;
    va0[md] = *(const bf16x8*)(vr + q * 8);
    va1[md] = *(const bf16x8*)(vr + 32 + q * 8);
  }
  // S^T = K*Q^T in two mk-halves (bounds live s-registers)
#pragma unroll
  for (int mh = 0; mh < 2; ++mh) {
    f32x4 s2[2][4];
    __builtin_amdgcn_s_setprio(1);
#pragma unroll
    for (int mk2 = 0; mk2 < 2; ++mk2)
#pragma unroll
      for (int nq = 0; nq < 4; ++nq) {
        f32x4 t = {0.f, 0.f, 0.f, 0.f};
        t = mfma16(ka0[mh * 2 + mk2], qf0[nq], t);
        t = mfma16(ka1[mh * 2 + mk2], qf1[nq], t);
        s2[mk2][nq] = t;
      }
    __builtin_amdgcn_s_setprio(0);
#pragma unroll
    for (int nq = 0; nq < 4; ++nq)
#pragma unroll
      for (int mk2 = 0; mk2 < 2; ++mk2) {
        const int mk = mh * 2 + mk2;
        bf16x4 pk;
#pragma unroll
        for (int r = 0; r < 4; ++r) {
          float pv = __builtin_amdgcn_exp2f(s2[mk2][nq][r] * c1 - 16.0f);
          if (DIAG && (mk * 16 + q * 4 + r) > (nq * 16 + l15)) pv = 0.f;
          rs[nq] += pv;
          pk[r] = (bf16_t)pv;
        }
        *(bf16x4*)(ps + nq * 1152 + l15 * 72 + mk * 16 + q * 4) = pk;
      }
  }
  // O^T += V^T * P
#pragma unroll
  for (int nq = 0; nq < 4; ++nq) {
    bf16x8 pb0 = *(const bf16x8*)(ps + nq * 1152 + l15 * 72 + q * 8);
    bf16x8 pb1 = *(const bf16x8*)(ps + nq * 1152 + l15 * 72 + 32 + q * 8);
    __builtin_amdgcn_s_setprio(1);
#pragma unroll
    for (int md = 0; md < 4; ++md) {
      o[md][nq] = mfma16(va0[md], pb0, o[md][nq]);
      o[md][nq] = mfma16(va1[md], pb1, o[md][nq]);
    }
    __builtin_amdgcn_s_setprio(0);
  }
}

__device__ __forceinline__ void stash_partial(float* __restrict__ cb, int l,
                                              const f32x4 (&o)[4][4],
                                              const float (&rs)[4]) {
#pragma unroll
  for (int md = 0; md < 4; ++md)
#pragma unroll
    for (int nq = 0; nq < 4; ++nq)
      *(f32x4*)&cb[((md * 4 + nq) * 64 + l) * 4] = o[md][nq];
#pragma unroll
  for (int nq = 0; nq < 4; ++nq) cb[4096 + l * 4 + nq] = rs[nq];
}

__device__ __forceinline__ void accum_partial(const float* __restrict__ cb, int l,
                                              f32x4 (&o)[4][4], float (&rs)[4]) {
#pragma unroll
  for (int md = 0; md < 4; ++md)
#pragma unroll
    for (int nq = 0; nq < 4; ++nq)
      o[md][nq] += *(const f32x4*)&cb[((md * 4 + nq) * 64 + l) * 4];
#pragma unroll
  for (int nq = 0; nq < 4; ++nq) rs[nq] += cb[4096 + l * 4 + nq];
}

__device__ __forceinline__ void attn_finalize(bf16_t* __restrict__ AO, int b, int h,
                                              int qt, int l15, int q,
                                              f32x4 (&o)[4][4], float (&rs)[4]) {
#pragma unroll
  for (int nq = 0; nq < 4; ++nq) {
    rs[nq] += __shfl_xor(rs[nq], 16);
    rs[nq] += __shfl_xor(rs[nq], 32);
  }
  float inv[4];
#pragma unroll
  for (int nq = 0; nq < 4; ++nq) inv[nq] = 1.f / rs[nq];
#pragma unroll
  for (int md = 0; md < 4; ++md)
#pragma unroll
    for (int nq = 0; nq < 4; ++nq) {
      bf16x4 ov = {(bf16_t)(o[md][nq][0] * inv[nq]), (bf16_t)(o[md][nq][1] * inv[nq]),
                   (bf16_t)(o[md][nq][2] * inv[nq]), (bf16_t)(o[md][nq][3] * inv[nq])};
      *(bf16x4*)(AO + (size_t)(b * 2048 + qt * 64 + nq * 16 + l15) * 1024 +
                 h * 64 + md * 16 + q * 4) = ov;
    }
}

__global__ __launch_bounds__(256, 2)
void mqa_attn12(const bf16_t* __restrict__ Qb, const bf16_t* __restrict__ KVb,
                const bf16_t* __restrict__ VtG, bf16_t* __restrict__ AO) {
  __shared__ __align__(16) bf16_t Ps[4][4][16 * 72];  // 36.9 KB; combine buf after loop
  const int u = blockIdx.x;
  const int b = u & 3;                 // one batch per XCD L2
  const int h = (u >> 2) & 15;
  const int qt = 31 - (u >> 6);        // heavy blocks dispatched first
  const int w = threadIdx.x >> 6, l = threadIdx.x & 63;
  const int l15 = l & 15, q = l >> 4;
  bf16_t* ps = &Ps[w][0][0];
  const bf16_t* kbase = KVb + (size_t)b * 2048 * 128;
  const bf16_t* vbase = VtG + (size_t)b * 64 * 2048;

  bf16x8 qf0[4], qf1[4];
  f32x4 o[4][4] = {};
  float rs[4] = {0.f, 0.f, 0.f, 0.f};

  load_q(Qb, b, h, qt, l15, q, qf0, qf1);
  // wave w: kt == w (mod 4), nondiag below qt; diag at qt if parity matches
  for (int kt = w; kt < qt; kt += 4)
    attn_step<false>(kbase, vbase, kt, l15, q, ps, qf0, qf1, o, rs);
  if ((qt & 3) == w)
    attn_step<true>(kbase, vbase, qt, l15, q, ps, qf0, qf1, o, rs);

  // in-block combine through dead Ps: A=Ps[0..1] (18.4KB), B=Ps[2..3]
  float* cbA = (float*)&Ps[0][0][0];
  float* cbB = (float*)&Ps[2][0][0];
  __syncthreads();                       // all loops done; Ps dead
  if (w == 1) stash_partial(cbA, l, o, rs);
  if (w == 3) stash_partial(cbB, l, o, rs);
  __syncthreads();
  if (w == 0) accum_partial(cbA, l, o, rs);
  if (w == 2) accum_partial(cbB, l, o, rs);
  __syncthreads();
  if (w == 2) stash_partial(cbA, l, o, rs);
  __syncthreads();
  if (w == 0) {
    accum_partial(cbA, l, o, rs);
    attn_finalize(AO, b, h, qt, l15, q, o, rs);
  }
}

extern "C" void kernel_launch(void* const* d_in, const int* in_sizes, int n_in,
                              void* d_out, int out_size, void* d_ws, size_t ws_size,
                              hipStream_t stream) {
  (void)in_sizes; (void)n_in; (void)out_size; (void)ws_size;
  const int BS = 8192;  // B*S
  const float* x  = (const float*)d_in[0];
  const float* Wq = (const float*)d_in[1];
  const float* bq = (const float*)d_in[2];
  const float* Wk = (const float*)d_in[3];
  const float* bk = (const float*)d_in[4];
  const float* Wv = (const float*)d_in[5];
  const float* bv = (const float*)d_in[6];
  const float* Wo = (const float*)d_in[7];
  const float* bo = (const float*)d_in[8];
  float* out = (float*)d_out;

  bf16_t* p = (bf16_t*)d_ws;
  bf16_t* WqT  = p; p += 1024 * 1024;  // rows 0-1023 of fused Bt
  bf16_t* WkvT = p; p += 128 * 1024;   // rows 1024-1151 (contiguous after WqT)
  bf16_t* WoT  = p; p += 1024 * 1024;
  bf16_t* xb   = p; p += (size_t)BS * 1024;
  bf16_t* Qb   = p; p += (size_t)BS * 1024;
  bf16_t* KVb  = p; p += (size_t)BS * 128;   // cols 0-63 = K, 64-127 = V
  bf16_t* VtG  = p; p += (size_t)4 * 64 * 2048;
  float*  bqkv = (float*)p; p += 2304;       // 1152 f32
  bf16_t* AO  = xb;   // x dead after projections

  // 4 launches: prep, fused QKV gemm (+V^T side-write), attn, O gemm.
  prep<<<dim3(546 + 8192), 256, 0, stream>>>(x, Wq, Wk, Wv, Wo, bq, bk, bv,
                                             xb, WqT, WkvT, WoT, bqkv);

  gemm_qkv<<<dim3(BS / 128, 9), 256, 0, stream>>>(xb, WqT, bqkv, Qb, KVb, VtG, BS, 1024);

  mqa_attn12<<<dim3(2048), 256, 0, stream>>>(Qb, KVb, VtG, AO);

  gemm_nt_bias_f32<<<dim3(BS / 128, 8), 256, 0, stream>>>(AO, WoT, bo, out, BS, 1024, 1024);
}

// Round 11
// 232.889 us; speedup vs baseline: 1.1684x; 1.0001x over previous
//
#include <hip/hip_runtime.h>
#include <hip/hip_bf16.h>

typedef __bf16 bf16_t;
typedef __bf16 bf16x4 __attribute__((ext_vector_type(4)));
typedef __bf16 bf16x8 __attribute__((ext_vector_type(8)));
typedef float f32x4 __attribute__((ext_vector_type(4)));

#define AS1(p) ((const __attribute__((address_space(1))) void*)(p))
#define AS3(p) ((__attribute__((address_space(3))) void*)(p))

__device__ __forceinline__ f32x4 mfma16(bf16x8 a, bf16x8 b, f32x4 c) {
  return __builtin_amdgcn_mfma_f32_16x16x32_bf16(a, b, c, 0, 0, 0);
}

// ---- fused prep: x cast + 4 weight transposes + combined bias build ----
__global__ void prep(const float* __restrict__ x, const float* __restrict__ Wq,
                     const float* __restrict__ Wk, const float* __restrict__ Wv,
                     const float* __restrict__ Wo, const float* __restrict__ bq,
                     const float* __restrict__ bk, const float* __restrict__ bv,
                     bf16_t* __restrict__ xb, bf16_t* __restrict__ WqT,
                     bf16_t* __restrict__ WkvT, bf16_t* __restrict__ WoT,
                     float* __restrict__ bqkv) {
  const int u = blockIdx.x;
  if (u >= 546) {  // x cast: 8192*1024 f32 -> bf16, 4/lane
    int i = ((u - 546) * 256 + threadIdx.x) * 4;
    float4 v = *(const float4*)(x + i);
    bf16x4 o = {(bf16_t)v.x, (bf16_t)v.y, (bf16_t)v.z, (bf16_t)v.w};
    *(bf16x4*)(xb + i) = o;
    return;
  }
  if (u == 544) {  // bq copy (1024 f32)
    int i = threadIdx.x * 4;
    *(float4*)(bqkv + i) = *(const float4*)(bq + i);
    return;
  }
  if (u == 545) {  // bk/bv pack
    if (threadIdx.x < 128)
      bqkv[1024 + threadIdx.x] =
          (threadIdx.x < 64) ? bk[threadIdx.x] : bv[threadIdx.x - 64];
    return;
  }
  const float* W; bf16_t* Wt; int N, bx, by;
  if (u < 256)      { W = Wq; Wt = WqT;              N = 1024; bx = u & 15;         by = u >> 4; }
  else if (u < 272) { W = Wk; Wt = WkvT;             N = 64;   bx = 0;              by = u - 256; }
  else if (u < 288) { W = Wv; Wt = WkvT + 64 * 1024; N = 64;   bx = 0;              by = u - 272; }
  else              { W = Wo; Wt = WoT;              N = 1024; bx = (u - 288) & 15; by = (u - 288) >> 4; }
  __shared__ float t[64][65];
  const int n0 = bx * 64, k0 = by * 64;
  const int tx = threadIdx.x & 63, ty = threadIdx.x >> 6;
#pragma unroll
  for (int i = 0; i < 16; ++i)
    t[ty * 16 + i][tx] = W[(size_t)(k0 + ty * 16 + i) * N + n0 + tx];
  __syncthreads();
#pragma unroll
  for (int i = 0; i < 16; ++i)
    Wt[(size_t)(n0 + ty * 16 + i) * 1024 + k0 + tx] = (bf16_t)t[tx][ty * 16 + i];
}

// Fused Q+KV projection, BK=64 (halves k-loop barrier/overhead count vs BK=32;
// two MFMAs per (mi,ni) consume k-halves 0-31/32-63 -- identical math to two
// BK=32 iterations). M-fastest grid (measured best, v11 post-mortem).
__global__ __launch_bounds__(256, 2)
void gemm_qkv(const bf16_t* __restrict__ A, const bf16_t* __restrict__ Bt,
              const float* __restrict__ bias, bf16_t* __restrict__ Qb,
              bf16_t* __restrict__ KVb, bf16_t* __restrict__ VtG, int M, int K) {
  __shared__ __align__(16) bf16_t As[128 * 64];
  __shared__ __align__(16) bf16_t Bs[128 * 64];
  const int tid = threadIdx.x;
  const int w = tid >> 6, l = tid & 63;
  const int l15 = l & 15, q = l >> 4;
  const int m0 = blockIdx.x * 128, n0 = blockIdx.y * 128;
  const int mw = (w >> 1) * 64, nw = (w & 1) * 64;
  f32x4 acc[4][4] = {};
  const int kb = (l & 7) * 8;  // 16B chunk within 64-col row
  int rA[4], rB[4];
#pragma unroll
  for (int i = 0; i < 4; ++i) {
    int row = (i * 4 + w) * 8 + (l >> 3);  // chunk ci = i*4+w covers rows ci*8..ci*8+7
    rA[i] = m0 + row;
    rB[i] = n0 + row;  // N=1152 = 9*128 exactly
  }
  for (int k0 = 0; k0 < K; k0 += 64) {
#pragma unroll
    for (int i = 0; i < 4; ++i) {
      int ci = i * 4 + w;
      __builtin_amdgcn_global_load_lds(AS1(A + (size_t)rA[i] * K + k0 + kb),
                                       AS3(As + ci * 512), 16, 0, 0);
      __builtin_amdgcn_global_load_lds(AS1(Bt + (size_t)rB[i] * K + k0 + kb),
                                       AS3(Bs + ci * 512), 16, 0, 0);
    }
    __syncthreads();
    bf16x8 af0[4], af1[4], bf0[4], bf1[4];
#pragma unroll
    for (int mi = 0; mi < 4; ++mi) {
      af0[mi] = *(const bf16x8*)(As + (mw + mi * 16 + l15) * 64 + q * 8);
      af1[mi] = *(const bf16x8*)(As + (mw + mi * 16 + l15) * 64 + 32 + q * 8);
    }
#pragma unroll
    for (int ni = 0; ni < 4; ++ni) {
      bf0[ni] = *(const bf16x8*)(Bs + (nw + ni * 16 + l15) * 64 + q * 8);
      bf1[ni] = *(const bf16x8*)(Bs + (nw + ni * 16 + l15) * 64 + 32 + q * 8);
    }
#pragma unroll
    for (int mi = 0; mi < 4; ++mi)
#pragma unroll
      for (int ni = 0; ni < 4; ++ni) {
        acc[mi][ni] = mfma16(af0[mi], bf0[ni], acc[mi][ni]);
        acc[mi][ni] = mfma16(af1[mi], bf1[ni], acc[mi][ni]);
      }
    __syncthreads();
  }
#pragma unroll
  for (int ni = 0; ni < 4; ++ni) {
    int col = n0 + nw + ni * 16 + l15;
    float bv = bias[col];
#pragma unroll
    for (int mi = 0; mi < 4; ++mi)
#pragma unroll
      for (int r = 0; r < 4; ++r) {
        int row = m0 + mw + mi * 16 + q * 4 + r;
        bf16_t v = (bf16_t)(acc[mi][ni][r] + bv);
        if (col < 1024) {
          Qb[(size_t)row * 1024 + col] = v;
        } else {
          int c2 = col - 1024;
          KVb[(size_t)row * 128 + c2] = v;
          if (c2 >= 64)
            VtG[(size_t)((row >> 11) * 64 + (c2 - 64)) * 2048 + (row & 2047)] = v;
        }
      }
  }
}

// O-projection GEMM, BK=64, M-fastest grid.
__global__ __launch_bounds__(256, 2)
void gemm_nt_bias_f32(const bf16_t* __restrict__ A, const bf16_t* __restrict__ Bt,
                      const float* __restrict__ bias, float* __restrict__ C,
                      int M, int N, int K) {
  __shared__ __align__(16) bf16_t As[128 * 64];
  __shared__ __align__(16) bf16_t Bs[128 * 64];
  const int tid = threadIdx.x;
  const int w = tid >> 6, l = tid & 63;
  const int l15 = l & 15, q = l >> 4;
  const int m0 = blockIdx.x * 128, n0 = blockIdx.y * 128;
  const int mw = (w >> 1) * 64, nw = (w & 1) * 64;
  f32x4 acc[4][4] = {};
  const int kb = (l & 7) * 8;
  int rA[4], rB[4];
#pragma unroll
  for (int i = 0; i < 4; ++i) {
    int row = (i * 4 + w) * 8 + (l >> 3);
    rA[i] = m0 + row;
    int rb = n0 + row; if (rb >= N) rb = N - 1;
    rB[i] = rb;
  }
  for (int k0 = 0; k0 < K; k0 += 64) {
#pragma unroll
    for (int i = 0; i < 4; ++i) {
      int ci = i * 4 + w;
      __builtin_amdgcn_global_load_lds(AS1(A + (size_t)rA[i] * K + k0 + kb),
                                       AS3(As + ci * 512), 16, 0, 0);
      __builtin_amdgcn_global_load_lds(AS1(Bt + (size_t)rB[i] * K + k0 + kb),
                                       AS3(Bs + ci * 512), 16, 0, 0);
    }
    __syncthreads();
    bf16x8 af0[4], af1[4], bf0[4], bf1[4];
#pragma unroll
    for (int mi = 0; mi < 4; ++mi) {
      af0[mi] = *(const bf16x8*)(As + (mw + mi * 16 + l15) * 64 + q * 8);
      af1[mi] = *(const bf16x8*)(As + (mw + mi * 16 + l15) * 64 + 32 + q * 8);
    }
#pragma unroll
    for (int ni = 0; ni < 4; ++ni) {
      bf0[ni] = *(const bf16x8*)(Bs + (nw + ni * 16 + l15) * 64 + q * 8);
      bf1[ni] = *(const bf16x8*)(Bs + (nw + ni * 16 + l15) * 64 + 32 + q * 8);
    }
#pragma unroll
    for (int mi = 0; mi < 4; ++mi)
#pragma unroll
      for (int ni = 0; ni < 4; ++ni) {
        acc[mi][ni] = mfma16(af0[mi], bf0[ni], acc[mi][ni]);
        acc[mi][ni] = mfma16(af1[mi], bf1[ni], acc[mi][ni]);
      }
    __syncthreads();
  }
#pragma unroll
  for (int ni = 0; ni < 4; ++ni) {
    int col = n0 + nw + ni * 16 + l15;
    if (col >= N) continue;
    float bv = bias[col];
#pragma unroll
    for (int mi = 0; mi < 4; ++mi)
#pragma unroll
      for (int r = 0; r < 4; ++r) {
        int row = m0 + mw + mi * 16 + q * 4 + r;
        C[(size_t)row * N + col] = acc[mi][ni][r] + bv;
      }
  }
}

// ---- MQA flash v9 attn (proven 77.3us, VGPR 112, no spill) ----
// v12 post-mortem: 4-wave kt-split ran 83.3us -- combine overhead + packing
// loss with NO occupancy gain (third failed TLP/ILP attempt: v8 output-split,
// v10 reg-dbuf spill at the 128-VGPR wall, v12 wave-split). v9 is the local
// optimum for this inner-loop structure; keep it verbatim.
__device__ __forceinline__ void load_q(const bf16_t* __restrict__ Qb, int b, int h,
                                       int qt, int l15, int q,
                                       bf16x8 (&qf0)[4], bf16x8 (&qf1)[4]) {
#pragma unroll
  for (int nq = 0; nq < 4; ++nq) {
    const bf16_t* qp = Qb + (size_t)(b * 2048 + qt * 64 + nq * 16 + l15) * 1024 + h * 64 + q * 8;
    qf0[nq] = *(const bf16x8*)qp;
    qf1[nq] = *(const bf16x8*)(qp + 32);
  }
}

template <bool DIAG>
__device__ __forceinline__ void attn_step(
    const bf16_t* __restrict__ kbase, const bf16_t* __restrict__ vbase, int kt,
    int l15, int q, bf16_t* __restrict__ ps,
    const bf16x8 (&qf0)[4], const bf16x8 (&qf1)[4],
    f32x4 (&o)[4][4], float (&rs)[4]) {
  const float c1 = 0.18033688f;  // log2(e)/8
  const bf16_t* kb = kbase + (size_t)kt * 64 * 128;  // K: cols 0-63 of KVb rows
  bf16x8 ka0[4], ka1[4];
#pragma unroll
  for (int mk = 0; mk < 4; ++mk) {
    const bf16_t* kr = kb + (mk * 16 + l15) * 128;
    ka0[mk] = *(const bf16x8*)(kr + q * 8);
    ka1[mk] = *(const bf16x8*)(kr + 32 + q * 8);
  }
  bf16x8 va0[4], va1[4];
#pragma unroll
  for (int md = 0; md < 4; ++md) {
    const bf16_t* vr = vbase + (size_t)(md * 16 + l15) * 2048 + kt * 64;
    va0[md] = *(const bf16x8*)(vr + q * 8);
    va1[md] = *(const bf16x8*)(vr + 32 + q * 8);
  }
  // S^T = K*Q^T in two mk-halves (bounds live s-registers)
#pragma unroll
  for (int mh = 0; mh < 2; ++mh) {
    f32x4 s2[2][4];
    __builtin_amdgcn_s_setprio(1);
#pragma unroll
    for (int mk2 = 0; mk2 < 2; ++mk2)
#pragma unroll
      for (int nq = 0; nq < 4; ++nq) {
        f32x4 t = {0.f, 0.f, 0.f, 0.f};
        t = mfma16(ka0[mh * 2 + mk2], qf0[nq], t);
        t = mfma16(ka1[mh * 2 + mk2], qf1[nq], t);
        s2[mk2][nq] = t;
      }
    __builtin_amdgcn_s_setprio(0);
#pragma unroll
    for (int nq = 0; nq < 4; ++nq)
#pragma unroll
      for (int mk2 = 0; mk2 < 2; ++mk2) {
        const int mk = mh * 2 + mk2;
        bf16x4 pk;
#pragma unroll
        for (int r = 0; r < 4; ++r) {
          float pv = __builtin_amdgcn_exp2f(s2[mk2][nq][r] * c1 - 16.0f);
          if (DIAG && (mk * 16 + q * 4 + r) > (nq * 16 + l15)) pv = 0.f;
          rs[nq] += pv;
          pk[r] = (bf16_t)pv;
        }
        *(bf16x4*)(ps + nq * 1152 + l15 * 72 + mk * 16 + q * 4) = pk;
      }
  }
  // O^T += V^T * P
#pragma unroll
  for (int nq = 0; nq < 4; ++nq) {
    bf16x8 pb0 = *(const bf16x8*)(ps + nq * 1152 + l15 * 72 + q * 8);
    bf16x8 pb1 = *(const bf16x8*)(ps + nq * 1152 + l15 * 72 + 32 + q * 8);
    __builtin_amdgcn_s_setprio(1);
#pragma unroll
    for (int md = 0; md < 4; ++md) {
      o[md][nq] = mfma16(va0[md], pb0, o[md][nq]);
      o[md][nq] = mfma16(va1[md], pb1, o[md][nq]);
    }
    __builtin_amdgcn_s_setprio(0);
  }
}

__device__ __forceinline__ void attn_finalize(bf16_t* __restrict__ AO, int b, int h,
                                              int qt, int l15, int q,
                                              f32x4 (&o)[4][4], float (&rs)[4]) {
#pragma unroll
  for (int nq = 0; nq < 4; ++nq) {
    rs[nq] += __shfl_xor(rs[nq], 16);
    rs[nq] += __shfl_xor(rs[nq], 32);
  }
  float inv[4];
#pragma unroll
  for (int nq = 0; nq < 4; ++nq) inv[nq] = 1.f / rs[nq];
#pragma unroll
  for (int md = 0; md < 4; ++md)
#pragma unroll
    for (int nq = 0; nq < 4; ++nq) {
      bf16x4 ov = {(bf16_t)(o[md][nq][0] * inv[nq]), (bf16_t)(o[md][nq][1] * inv[nq]),
                   (bf16_t)(o[md][nq][2] * inv[nq]), (bf16_t)(o[md][nq][3] * inv[nq])};
      *(bf16x4*)(AO + (size_t)(b * 2048 + qt * 64 + nq * 16 + l15) * 1024 +
                 h * 64 + md * 16 + q * 4) = ov;
    }
}

__global__ __launch_bounds__(128, 2)
void mqa_attn9(const bf16_t* __restrict__ Qb, const bf16_t* __restrict__ KVb,
               const bf16_t* __restrict__ VtG, bf16_t* __restrict__ AO) {
  __shared__ __align__(16) bf16_t Ps[2][4][16 * 72];  // 18 KB
  __shared__ __align__(16) float Oc[4096];            // 16 KB combine buffer
  __shared__ float RSc[256];                          // 1 KB
  const int u = blockIdx.x;
  const int b = u & 3;                 // one batch per XCD L2
  const int h = (u >> 2) & 15;
  const int p = (u >> 6) & 15;         // pair id; qt_h = 31-p, qt_l = p
  const int w = threadIdx.x >> 6, l = threadIdx.x & 63;
  const int l15 = l & 15, q = l >> 4;
  const int qt_h = 31 - p;
  bf16_t* ps = &Ps[w][0][0];
  const bf16_t* kbase = KVb + (size_t)b * 2048 * 128;
  const bf16_t* vbase = VtG + (size_t)b * 64 * 2048;

  bf16x8 qf0[4], qf1[4];
  f32x4 o[4][4] = {};
  float rs[4] = {0.f, 0.f, 0.f, 0.f};

  if (w == 0) {
    // first 17 steps of the heavy tile (diag included only when p==15)
    load_q(Qb, b, h, qt_h, l15, q, qf0, qf1);
    const int e = (p == 15) ? 16 : 17;
    for (int kt = 0; kt < e; ++kt)
      attn_step<false>(kbase, vbase, kt, l15, q, ps, qf0, qf1, o, rs);
    if (p == 15)
      attn_step<true>(kbase, vbase, 16, l15, q, ps, qf0, qf1, o, rs);
    __syncthreads();  // wave1's partial is in Oc/RSc
#pragma unroll
    for (int md = 0; md < 4; ++md)
#pragma unroll
      for (int nq = 0; nq < 4; ++nq)
        o[md][nq] += *(const f32x4*)&Oc[((md * 4 + nq) * 64 + l) * 4];
#pragma unroll
    for (int nq = 0; nq < 4; ++nq) rs[nq] += RSc[l * 4 + nq];
    attn_finalize(AO, b, h, qt_h, l15, q, o, rs);
  } else {
    // light tile complete (p steps + diag), written directly
    load_q(Qb, b, h, p, l15, q, qf0, qf1);
    for (int kt = 0; kt < p; ++kt)
      attn_step<false>(kbase, vbase, kt, l15, q, ps, qf0, qf1, o, rs);
    attn_step<true>(kbase, vbase, p, l15, q, ps, qf0, qf1, o, rs);
    attn_finalize(AO, b, h, p, l15, q, o, rs);
    // heavy-tile tail [17, 31-p] incl diag (empty when p==15)
#pragma unroll
    for (int md = 0; md < 4; ++md)
#pragma unroll
      for (int nq = 0; nq < 4; ++nq) o[md][nq] = f32x4{0.f, 0.f, 0.f, 0.f};
    rs[0] = rs[1] = rs[2] = rs[3] = 0.f;
    if (p < 15) {
      load_q(Qb, b, h, qt_h, l15, q, qf0, qf1);
      for (int kt = 17; kt < 31 - p; ++kt)
        attn_step<false>(kbase, vbase, kt, l15, q, ps, qf0, qf1, o, rs);
      attn_step<true>(kbase, vbase, 31 - p, l15, q, ps, qf0, qf1, o, rs);
    }
#pragma unroll
    for (int md = 0; md < 4; ++md)
#pragma unroll
      for (int nq = 0; nq < 4; ++nq)
        *(f32x4*)&Oc[((md * 4 + nq) * 64 + l) * 4] = o[md][nq];
#pragma unroll
    for (int nq = 0; nq < 4; ++nq) RSc[l * 4 + nq] = rs[nq];
    __syncthreads();  // release partial to wave0
  }
}

extern "C" void kernel_launch(void* const* d_in, const int* in_sizes, int n_in,
                              void* d_out, int out_size, void* d_ws, size_t ws_size,
                              hipStream_t stream) {
  (void)in_sizes; (void)n_in; (void)out_size; (void)ws_size;
  const int BS = 8192;  // B*S
  const float* x  = (const float*)d_in[0];
  const float* Wq = (const float*)d_in[1];
  const float* bq = (const float*)d_in[2];
  const float* Wk = (const float*)d_in[3];
  const float* bk = (const float*)d_in[4];
  const float* Wv = (const float*)d_in[5];
  const float* bv = (const float*)d_in[6];
  const float* Wo = (const float*)d_in[7];
  const float* bo = (const float*)d_in[8];
  float* out = (float*)d_out;

  bf16_t* p = (bf16_t*)d_ws;
  bf16_t* WqT  = p; p += 1024 * 1024;  // rows 0-1023 of fused Bt
  bf16_t* WkvT = p; p += 128 * 1024;   // rows 1024-1151 (contiguous after WqT)
  bf16_t* WoT  = p; p += 1024 * 1024;
  bf16_t* xb   = p; p += (size_t)BS * 1024;
  bf16_t* Qb   = p; p += (size_t)BS * 1024;
  bf16_t* KVb  = p; p += (size_t)BS * 128;   // cols 0-63 = K, 64-127 = V
  bf16_t* VtG  = p; p += (size_t)4 * 64 * 2048;
  float*  bqkv = (float*)p; p += 2304;       // 1152 f32
  bf16_t* AO  = xb;   // x dead after projections

  // 4 launches: prep, fused QKV gemm (+V^T side-write), attn, O gemm.
  prep<<<dim3(546 + 8192), 256, 0, stream>>>(x, Wq, Wk, Wv, Wo, bq, bk, bv,
                                             xb, WqT, WkvT, WoT, bqkv);

  gemm_qkv<<<dim3(BS / 128, 9), 256, 0, stream>>>(xb, WqT, bqkv, Qb, KVb, VtG, BS, 1024);

  mqa_attn9<<<dim3(1024), 128, 0, stream>>>(Qb, KVb, VtG, AO);

  gemm_nt_bias_f32<<<dim3(BS / 128, 8), 256, 0, stream>>>(AO, WoT, bo, out, BS, 1024, 1024);
}

// Round 12
// 227.574 us; speedup vs baseline: 1.1957x; 1.0234x over previous
//
#include <hip/hip_runtime.h>
#include <hip/hip_bf16.h>

typedef __bf16 bf16_t;
typedef __bf16 bf16x4 __attribute__((ext_vector_type(4)));
typedef __bf16 bf16x8 __attribute__((ext_vector_type(8)));
typedef float f32x4 __attribute__((ext_vector_type(4)));

#define AS1(p) ((const __attribute__((address_space(1))) void*)(p))
#define AS3(p) ((__attribute__((address_space(3))) void*)(p))

__device__ __forceinline__ f32x4 mfma16(bf16x8 a, bf16x8 b, f32x4 c) {
  return __builtin_amdgcn_mfma_f32_16x16x32_bf16(a, b, c, 0, 0, 0);
}

// ---- fused prep: x cast + 4 weight transposes + combined bias build ----
__global__ void prep(const float* __restrict__ x, const float* __restrict__ Wq,
                     const float* __restrict__ Wk, const float* __restrict__ Wv,
                     const float* __restrict__ Wo, const float* __restrict__ bq,
                     const float* __restrict__ bk, const float* __restrict__ bv,
                     bf16_t* __restrict__ xb, bf16_t* __restrict__ WqT,
                     bf16_t* __restrict__ WkvT, bf16_t* __restrict__ WoT,
                     float* __restrict__ bqkv) {
  const int u = blockIdx.x;
  if (u >= 546) {  // x cast: 8192*1024 f32 -> bf16, 4/lane
    int i = ((u - 546) * 256 + threadIdx.x) * 4;
    float4 v = *(const float4*)(x + i);
    bf16x4 o = {(bf16_t)v.x, (bf16_t)v.y, (bf16_t)v.z, (bf16_t)v.w};
    *(bf16x4*)(xb + i) = o;
    return;
  }
  if (u == 544) {  // bq copy (1024 f32)
    int i = threadIdx.x * 4;
    *(float4*)(bqkv + i) = *(const float4*)(bq + i);
    return;
  }
  if (u == 545) {  // bk/bv pack
    if (threadIdx.x < 128)
      bqkv[1024 + threadIdx.x] =
          (threadIdx.x < 64) ? bk[threadIdx.x] : bv[threadIdx.x - 64];
    return;
  }
  const float* W; bf16_t* Wt; int N, bx, by;
  if (u < 256)      { W = Wq; Wt = WqT;              N = 1024; bx = u & 15;         by = u >> 4; }
  else if (u < 272) { W = Wk; Wt = WkvT;             N = 64;   bx = 0;              by = u - 256; }
  else if (u < 288) { W = Wv; Wt = WkvT + 64 * 1024; N = 64;   bx = 0;              by = u - 272; }
  else              { W = Wo; Wt = WoT;              N = 1024; bx = (u - 288) & 15; by = (u - 288) >> 4; }
  __shared__ float t[64][65];
  const int n0 = bx * 64, k0 = by * 64;
  const int tx = threadIdx.x & 63, ty = threadIdx.x >> 6;
#pragma unroll
  for (int i = 0; i < 16; ++i)
    t[ty * 16 + i][tx] = W[(size_t)(k0 + ty * 16 + i) * N + n0 + tx];
  __syncthreads();
#pragma unroll
  for (int i = 0; i < 16; ++i)
    Wt[(size_t)(n0 + ty * 16 + i) * 1024 + k0 + tx] = (bf16_t)t[tx][ty * 16 + i];
}

// Fused Q+KV projection, BK=32 (BK=64 measured ~6us WORSE, reverted) with
// T3-lite double-buffered staging: one barrier per k-iter; stage(t+1) issued
// BEFORE compute(t) so global_load_lds latency hides under the MFMAs. At our
// 2.25 blocks/CU (grid 576) wave-level overlap is thin, so issue-early
// staging matters more than at m99's 3-4 blocks/CU where it was neutral.
__global__ __launch_bounds__(256, 2)
void gemm_qkv(const bf16_t* __restrict__ A, const bf16_t* __restrict__ Bt,
              const float* __restrict__ bias, bf16_t* __restrict__ Qb,
              bf16_t* __restrict__ KVb, bf16_t* __restrict__ VtG, int M, int K) {
  __shared__ __align__(16) bf16_t As[2][128 * 32];
  __shared__ __align__(16) bf16_t Bs[2][128 * 32];
  const int tid = threadIdx.x;
  const int w = tid >> 6, l = tid & 63;
  const int l15 = l & 15, q = l >> 4;
  const int m0 = blockIdx.x * 128, n0 = blockIdx.y * 128;
  const int mw = (w >> 1) * 64, nw = (w & 1) * 64;
  f32x4 acc[4][4] = {};
  const int kb = (l & 3) * 8;
  int rA[2], rB[2];
#pragma unroll
  for (int i = 0; i < 2; ++i) {
    int row = (i * 4 + w) * 16 + (l >> 2);
    rA[i] = m0 + row;
    rB[i] = n0 + row;  // N=1152 = 9*128 exactly
  }
  // prologue: stage tile 0 into buffer 0
#pragma unroll
  for (int i = 0; i < 2; ++i) {
    int sg = i * 4 + w;
    __builtin_amdgcn_global_load_lds(AS1(A + (size_t)rA[i] * K + kb),
                                     AS3(&As[0][0] + sg * 512), 16, 0, 0);
    __builtin_amdgcn_global_load_lds(AS1(Bt + (size_t)rB[i] * K + kb),
                                     AS3(&Bs[0][0] + sg * 512), 16, 0, 0);
  }
  const int NT = K / 32;
  for (int t = 0; t < NT; ++t) {
    __syncthreads();  // drains stage(t) (vmcnt in barrier); syncs all waves
    const int cur = t & 1;
    if (t + 1 < NT) {  // stage next tile; loads fly during compute below
      const int k0n = (t + 1) * 32;
#pragma unroll
      for (int i = 0; i < 2; ++i) {
        int sg = i * 4 + w;
        __builtin_amdgcn_global_load_lds(AS1(A + (size_t)rA[i] * K + k0n + kb),
                                         AS3(&As[cur ^ 1][0] + sg * 512), 16, 0, 0);
        __builtin_amdgcn_global_load_lds(AS1(Bt + (size_t)rB[i] * K + k0n + kb),
                                         AS3(&Bs[cur ^ 1][0] + sg * 512), 16, 0, 0);
      }
    }
    bf16x8 af[4], bfr[4];
#pragma unroll
    for (int mi = 0; mi < 4; ++mi)
      af[mi] = *(const bf16x8*)(&As[cur][0] + (mw + mi * 16 + l15) * 32 + q * 8);
#pragma unroll
    for (int ni = 0; ni < 4; ++ni)
      bfr[ni] = *(const bf16x8*)(&Bs[cur][0] + (nw + ni * 16 + l15) * 32 + q * 8);
#pragma unroll
    for (int mi = 0; mi < 4; ++mi)
#pragma unroll
      for (int ni = 0; ni < 4; ++ni)
        acc[mi][ni] = mfma16(af[mi], bfr[ni], acc[mi][ni]);
  }
#pragma unroll
  for (int ni = 0; ni < 4; ++ni) {
    int col = n0 + nw + ni * 16 + l15;
    float bv = bias[col];
#pragma unroll
    for (int mi = 0; mi < 4; ++mi)
#pragma unroll
      for (int r = 0; r < 4; ++r) {
        int row = m0 + mw + mi * 16 + q * 4 + r;
        bf16_t v = (bf16_t)(acc[mi][ni][r] + bv);
        if (col < 1024) {
          Qb[(size_t)row * 1024 + col] = v;
        } else {
          int c2 = col - 1024;
          KVb[(size_t)row * 128 + c2] = v;
          if (c2 >= 64)
            VtG[(size_t)((row >> 11) * 64 + (c2 - 64)) * 2048 + (row & 2047)] = v;
        }
      }
  }
}

// O-projection GEMM, BK=32 + T3-lite dbuf, M-fastest grid.
__global__ __launch_bounds__(256, 2)
void gemm_nt_bias_f32(const bf16_t* __restrict__ A, const bf16_t* __restrict__ Bt,
                      const float* __restrict__ bias, float* __restrict__ C,
                      int M, int N, int K) {
  __shared__ __align__(16) bf16_t As[2][128 * 32];
  __shared__ __align__(16) bf16_t Bs[2][128 * 32];
  const int tid = threadIdx.x;
  const int w = tid >> 6, l = tid & 63;
  const int l15 = l & 15, q = l >> 4;
  const int m0 = blockIdx.x * 128, n0 = blockIdx.y * 128;
  const int mw = (w >> 1) * 64, nw = (w & 1) * 64;
  f32x4 acc[4][4] = {};
  const int kb = (l & 3) * 8;
  int rA[2], rB[2];
#pragma unroll
  for (int i = 0; i < 2; ++i) {
    int row = (i * 4 + w) * 16 + (l >> 2);
    rA[i] = m0 + row;
    int rb = n0 + row; if (rb >= N) rb = N - 1;
    rB[i] = rb;
  }
#pragma unroll
  for (int i = 0; i < 2; ++i) {
    int sg = i * 4 + w;
    __builtin_amdgcn_global_load_lds(AS1(A + (size_t)rA[i] * K + kb),
                                     AS3(&As[0][0] + sg * 512), 16, 0, 0);
    __builtin_amdgcn_global_load_lds(AS1(Bt + (size_t)rB[i] * K + kb),
                                     AS3(&Bs[0][0] + sg * 512), 16, 0, 0);
  }
  const int NT = K / 32;
  for (int t = 0; t < NT; ++t) {
    __syncthreads();
    const int cur = t & 1;
    if (t + 1 < NT) {
      const int k0n = (t + 1) * 32;
#pragma unroll
      for (int i = 0; i < 2; ++i) {
        int sg = i * 4 + w;
        __builtin_amdgcn_global_load_lds(AS1(A + (size_t)rA[i] * K + k0n + kb),
                                         AS3(&As[cur ^ 1][0] + sg * 512), 16, 0, 0);
        __builtin_amdgcn_global_load_lds(AS1(Bt + (size_t)rB[i] * K + k0n + kb),
                                         AS3(&Bs[cur ^ 1][0] + sg * 512), 16, 0, 0);
      }
    }
    bf16x8 af[4], bfr[4];
#pragma unroll
    for (int mi = 0; mi < 4; ++mi)
      af[mi] = *(const bf16x8*)(&As[cur][0] + (mw + mi * 16 + l15) * 32 + q * 8);
#pragma unroll
    for (int ni = 0; ni < 4; ++ni)
      bfr[ni] = *(const bf16x8*)(&Bs[cur][0] + (nw + ni * 16 + l15) * 32 + q * 8);
#pragma unroll
    for (int mi = 0; mi < 4; ++mi)
#pragma unroll
      for (int ni = 0; ni < 4; ++ni)
        acc[mi][ni] = mfma16(af[mi], bfr[ni], acc[mi][ni]);
  }
#pragma unroll
  for (int ni = 0; ni < 4; ++ni) {
    int col = n0 + nw + ni * 16 + l15;
    if (col >= N) continue;
    float bv = bias[col];
#pragma unroll
    for (int mi = 0; mi < 4; ++mi)
#pragma unroll
      for (int r = 0; r < 4; ++r) {
        int row = m0 + mw + mi * 16 + q * 4 + r;
        C[(size_t)row * N + col] = acc[mi][ni][r] + bv;
      }
  }
}

// ---- MQA flash v9 attn (proven 77.3us, VGPR 112, no spill) -- verbatim ----
__device__ __forceinline__ void load_q(const bf16_t* __restrict__ Qb, int b, int h,
                                       int qt, int l15, int q,
                                       bf16x8 (&qf0)[4], bf16x8 (&qf1)[4]) {
#pragma unroll
  for (int nq = 0; nq < 4; ++nq) {
    const bf16_t* qp = Qb + (size_t)(b * 2048 + qt * 64 + nq * 16 + l15) * 1024 + h * 64 + q * 8;
    qf0[nq] = *(const bf16x8*)qp;
    qf1[nq] = *(const bf16x8*)(qp + 32);
  }
}

template <bool DIAG>
__device__ __forceinline__ void attn_step(
    const bf16_t* __restrict__ kbase, const bf16_t* __restrict__ vbase, int kt,
    int l15, int q, bf16_t* __restrict__ ps,
    const bf16x8 (&qf0)[4], const bf16x8 (&qf1)[4],
    f32x4 (&o)[4][4], float (&rs)[4]) {
  const float c1 = 0.18033688f;  // log2(e)/8
  const bf16_t* kb = kbase + (size_t)kt * 64 * 128;  // K: cols 0-63 of KVb rows
  bf16x8 ka0[4], ka1[4];
#pragma unroll
  for (int mk = 0; mk < 4; ++mk) {
    const bf16_t* kr = kb + (mk * 16 + l15) * 128;
    ka0[mk] = *(const bf16x8*)(kr + q * 8);
    ka1[mk] = *(const bf16x8*)(kr + 32 + q * 8);
  }
  bf16x8 va0[4], va1[4];
#pragma unroll
  for (int md = 0; md < 4; ++md) {
    const bf16_t* vr = vbase + (size_t)(md * 16 + l15) * 2048 + kt * 64;
    va0[md] = *(const bf16x8*)(vr + q * 8);
    va1[md] = *(const bf16x8*)(vr + 32 + q * 8);
  }
  // S^T = K*Q^T in two mk-halves (bounds live s-registers)
#pragma unroll
  for (int mh = 0; mh < 2; ++mh) {
    f32x4 s2[2][4];
    __builtin_amdgcn_s_setprio(1);
#pragma unroll
    for (int mk2 = 0; mk2 < 2; ++mk2)
#pragma unroll
      for (int nq = 0; nq < 4; ++nq) {
        f32x4 t = {0.f, 0.f, 0.f, 0.f};
        t = mfma16(ka0[mh * 2 + mk2], qf0[nq], t);
        t = mfma16(ka1[mh * 2 + mk2], qf1[nq], t);
        s2[mk2][nq] = t;
      }
    __builtin_amdgcn_s_setprio(0);
#pragma unroll
    for (int nq = 0; nq < 4; ++nq)
#pragma unroll
      for (int mk2 = 0; mk2 < 2; ++mk2) {
        const int mk = mh * 2 + mk2;
        bf16x4 pk;
#pragma unroll
        for (int r = 0; r < 4; ++r) {
          float pv = __builtin_amdgcn_exp2f(s2[mk2][nq][r] * c1 - 16.0f);
          if (DIAG && (mk * 16 + q * 4 + r) > (nq * 16 + l15)) pv = 0.f;
          rs[nq] += pv;
          pk[r] = (bf16_t)pv;
        }
        *(bf16x4*)(ps + nq * 1152 + l15 * 72 + mk * 16 + q * 4) = pk;
      }
  }
  // O^T += V^T * P
#pragma unroll
  for (int nq = 0; nq < 4; ++nq) {
    bf16x8 pb0 = *(const bf16x8*)(ps + nq * 1152 + l15 * 72 + q * 8);
    bf16x8 pb1 = *(const bf16x8*)(ps + nq * 1152 + l15 * 72 + 32 + q * 8);
    __builtin_amdgcn_s_setprio(1);
#pragma unroll
    for (int md = 0; md < 4; ++md) {
      o[md][nq] = mfma16(va0[md], pb0, o[md][nq]);
      o[md][nq] = mfma16(va1[md], pb1, o[md][nq]);
    }
    __builtin_amdgcn_s_setprio(0);
  }
}

__device__ __forceinline__ void attn_finalize(bf16_t* __restrict__ AO, int b, int h,
                                              int qt, int l15, int q,
                                              f32x4 (&o)[4][4], float (&rs)[4]) {
#pragma unroll
  for (int nq = 0; nq < 4; ++nq) {
    rs[nq] += __shfl_xor(rs[nq], 16);
    rs[nq] += __shfl_xor(rs[nq], 32);
  }
  float inv[4];
#pragma unroll
  for (int nq = 0; nq < 4; ++nq) inv[nq] = 1.f / rs[nq];
#pragma unroll
  for (int md = 0; md < 4; ++md)
#pragma unroll
    for (int nq = 0; nq < 4; ++nq) {
      bf16x4 ov = {(bf16_t)(o[md][nq][0] * inv[nq]), (bf16_t)(o[md][nq][1] * inv[nq]),
                   (bf16_t)(o[md][nq][2] * inv[nq]), (bf16_t)(o[md][nq][3] * inv[nq])};
      *(bf16x4*)(AO + (size_t)(b * 2048 + qt * 64 + nq * 16 + l15) * 1024 +
                 h * 64 + md * 16 + q * 4) = ov;
    }
}

__global__ __launch_bounds__(128, 2)
void mqa_attn9(const bf16_t* __restrict__ Qb, const bf16_t* __restrict__ KVb,
               const bf16_t* __restrict__ VtG, bf16_t* __restrict__ AO) {
  __shared__ __align__(16) bf16_t Ps[2][4][16 * 72];  // 18 KB
  __shared__ __align__(16) float Oc[4096];            // 16 KB combine buffer
  __shared__ float RSc[256];                          // 1 KB
  const int u = blockIdx.x;
  const int b = u & 3;                 // one batch per XCD L2
  const int h = (u >> 2) & 15;
  const int p = (u >> 6) & 15;         // pair id; qt_h = 31-p, qt_l = p
  const int w = threadIdx.x >> 6, l = threadIdx.x & 63;
  const int l15 = l & 15, q = l >> 4;
  const int qt_h = 31 - p;
  bf16_t* ps = &Ps[w][0][0];
  const bf16_t* kbase = KVb + (size_t)b * 2048 * 128;
  const bf16_t* vbase = VtG + (size_t)b * 64 * 2048;

  bf16x8 qf0[4], qf1[4];
  f32x4 o[4][4] = {};
  float rs[4] = {0.f, 0.f, 0.f, 0.f};

  if (w == 0) {
    // first 17 steps of the heavy tile (diag included only when p==15)
    load_q(Qb, b, h, qt_h, l15, q, qf0, qf1);
    const int e = (p == 15) ? 16 : 17;
    for (int kt = 0; kt < e; ++kt)
      attn_step<false>(kbase, vbase, kt, l15, q, ps, qf0, qf1, o, rs);
    if (p == 15)
      attn_step<true>(kbase, vbase, 16, l15, q, ps, qf0, qf1, o, rs);
    __syncthreads();  // wave1's partial is in Oc/RSc
#pragma unroll
    for (int md = 0; md < 4; ++md)
#pragma unroll
      for (int nq = 0; nq < 4; ++nq)
        o[md][nq] += *(const f32x4*)&Oc[((md * 4 + nq) * 64 + l) * 4];
#pragma unroll
    for (int nq = 0; nq < 4; ++nq) rs[nq] += RSc[l * 4 + nq];
    attn_finalize(AO, b, h, qt_h, l15, q, o, rs);
  } else {
    // light tile complete (p steps + diag), written directly
    load_q(Qb, b, h, p, l15, q, qf0, qf1);
    for (int kt = 0; kt < p; ++kt)
      attn_step<false>(kbase, vbase, kt, l15, q, ps, qf0, qf1, o, rs);
    attn_step<true>(kbase, vbase, p, l15, q, ps, qf0, qf1, o, rs);
    attn_finalize(AO, b, h, p, l15, q, o, rs);
    // heavy-tile tail [17, 31-p] incl diag (empty when p==15)
#pragma unroll
    for (int md = 0; md < 4; ++md)
#pragma unroll
      for (int nq = 0; nq < 4; ++nq) o[md][nq] = f32x4{0.f, 0.f, 0.f, 0.f};
    rs[0] = rs[1] = rs[2] = rs[3] = 0.f;
    if (p < 15) {
      load_q(Qb, b, h, qt_h, l15, q, qf0, qf1);
      for (int kt = 17; kt < 31 - p; ++kt)
        attn_step<false>(kbase, vbase, kt, l15, q, ps, qf0, qf1, o, rs);
      attn_step<true>(kbase, vbase, 31 - p, l15, q, ps, qf0, qf1, o, rs);
    }
#pragma unroll
    for (int md = 0; md < 4; ++md)
#pragma unroll
      for (int nq = 0; nq < 4; ++nq)
        *(f32x4*)&Oc[((md * 4 + nq) * 64 + l) * 4] = o[md][nq];
#pragma unroll
    for (int nq = 0; nq < 4; ++nq) RSc[l * 4 + nq] = rs[nq];
    __syncthreads();  // release partial to wave0
  }
}

extern "C" void kernel_launch(void* const* d_in, const int* in_sizes, int n_in,
                              void* d_out, int out_size, void* d_ws, size_t ws_size,
                              hipStream_t stream) {
  (void)in_sizes; (void)n_in; (void)out_size; (void)ws_size;
  const int BS = 8192;  // B*S
  const float* x  = (const float*)d_in[0];
  const float* Wq = (const float*)d_in[1];
  const float* bq = (const float*)d_in[2];
  const float* Wk = (const float*)d_in[3];
  const float* bk = (const float*)d_in[4];
  const float* Wv = (const float*)d_in[5];
  const float* bv = (const float*)d_in[6];
  const float* Wo = (const float*)d_in[7];
  const float* bo = (const float*)d_in[8];
  float* out = (float*)d_out;

  bf16_t* p = (bf16_t*)d_ws;
  bf16_t* WqT  = p; p += 1024 * 1024;  // rows 0-1023 of fused Bt
  bf16_t* WkvT = p; p += 128 * 1024;   // rows 1024-1151 (contiguous after WqT)
  bf16_t* WoT  = p; p += 1024 * 1024;
  bf16_t* xb   = p; p += (size_t)BS * 1024;
  bf16_t* Qb   = p; p += (size_t)BS * 1024;
  bf16_t* KVb  = p; p += (size_t)BS * 128;   // cols 0-63 = K, 64-127 = V
  bf16_t* VtG  = p; p += (size_t)4 * 64 * 2048;
  float*  bqkv = (float*)p; p += 2304;       // 1152 f32
  bf16_t* AO  = xb;   // x dead after projections

  // 4 launches: prep, fused QKV gemm (+V^T side-write), attn, O gemm.
  prep<<<dim3(546 + 8192), 256, 0, stream>>>(x, Wq, Wk, Wv, Wo, bq, bk, bv,
                                             xb, WqT, WkvT, WoT, bqkv);

  gemm_qkv<<<dim3(BS / 128, 9), 256, 0, stream>>>(xb, WqT, bqkv, Qb, KVb, VtG, BS, 1024);

  mqa_attn9<<<dim3(1024), 128, 0, stream>>>(Qb, KVb, VtG, AO);

  gemm_nt_bias_f32<<<dim3(BS / 128, 8), 256, 0, stream>>>(AO, WoT, bo, out, BS, 1024, 1024);
}